// Round 1
// baseline (153.629 us; speedup 1.0000x reference)
//
#include <hip/hip_runtime.h>
#include <math.h>

// One thread per batch element. Each element runs 50 Adam steps on a
// 3-parameter problem with an analytic gradient of the 5-wavelength
// radiative-transfer forward model. All state lives in registers.
//
// Gradient derivation:
//   a[l]  = A0 + Aph[l]*chla + Acd[l]*cdom + Anap*nap
//   bb[l] = B0 + Bph[l]*chla + Bnap*nap
//   u = bb/(a+bb),  rrs = (c1 + c2*u)*u,  r[l] = rrs*E[l] - Y[l]
//   dr/dch_k = E[l]*(c1 + 2*c2*u) * (dbb_k*a - da_k*bb)/s^2   (s = a+bb)
//   g = J^T * Sym(S_e) * r + Sym(S_a) * (ch - x_a)    (Sym(S)=0.5(S+S^T),
//   which is what jax.grad of the quadratic form produces)

__global__ __launch_bounds__(256)
void pe_kernel(const float* __restrict__ X,      // (B,5,5)
               const float* __restrict__ Y,      // (B,5)
               const float* __restrict__ ch0p,   // (B,1,3)
               const float* __restrict__ pf,     // (14,)
               const float* __restrict__ x_a,    // (3,)
               const float* __restrict__ s_a_inv,// (3,3)
               const float* __restrict__ s_e_inv,// (5,5)
               const int*   __restrict__ n_iter, // (1,)
               float* __restrict__ out,          // (B,9)
               int B)
{
    const int b = blockIdx.x * blockDim.x + threadIdx.x;
    if (b >= B) return;

    const float lam[5] = {-0.275f, 0.025f, 0.5f, 0.7f, 1.15f};

    // Uniform small arrays (compiler keeps these in SGPRs via scalar loads).
    float pfv[14];
#pragma unroll
    for (int i = 0; i < 14; ++i) pfv[i] = pf[i];

    const float xa0 = x_a[0], xa1 = x_a[1], xa2 = x_a[2];

    float Sa[3][3];
#pragma unroll
    for (int i = 0; i < 3; ++i)
#pragma unroll
        for (int j = 0; j < 3; ++j)
            Sa[i][j] = 0.5f * (s_a_inv[i*3+j] + s_a_inv[j*3+i]);

    float Se[5][5];
#pragma unroll
    for (int i = 0; i < 5; ++i)
#pragma unroll
        for (int j = 0; j < 5; ++j)
            Se[i][j] = 0.5f * (s_e_inv[i*5+j] + s_e_inv[j*5+i]);

    const int T = n_iter[0];

    // Iteration-invariant optics constants.
    const float A0   = 0.0045f, Bb0 = 0.0012f;
    const float Anap = pfv[12] * 0.005f;
    const float Bnap = pfv[13] * 0.005f;
    const float c1   = pfv[7] * 0.089f;
    const float c2   = pfv[8] * 0.1245f;
    float Aph[5], Acd[5], Bph[5];
#pragma unroll
    for (int l = 0; l < 5; ++l) {
        Aph[l] = pfv[0] * 0.05f * (1.0f + pfv[1] * 0.1f * lam[l] + pfv[2] * 0.01f);
        Acd[l] = pfv[5] * 0.1f * expf(-pfv[6] * 1.7f * lam[l]);
        Bph[l] = pfv[3] * 0.001f * (1.0f + pfv[4] * 0.05f * lam[l]);
    }

    // Per-element iteration-invariant data.
    float E[5], Yv[5], x3[5];
#pragma unroll
    for (int l = 0; l < 5; ++l) {
        const float Edir = X[b*25 + l*5 + 0];
        const float Edif = X[b*25 + l*5 + 1];
        x3[l] = X[b*25 + l*5 + 3];
        E[l]  = (Edir + 0.5f * Edif) / (Edir + Edif);
        Yv[l] = Y[b*5 + l];
    }

    float ch0v = ch0p[b*3 + 0];
    float ch1v = ch0p[b*3 + 1];
    float ch2v = ch0p[b*3 + 2];

    float m0 = 0.f, m1 = 0.f, m2 = 0.f;
    float v0 = 0.f, v1 = 0.f, v2 = 0.f;
    float p1 = 1.0f, p2 = 1.0f;   // running b1^t, b2^t

    const float B1c = 0.9f,  oB1 = 1.0f - 0.9f;     // match JAX float32 consts
    const float B2c = 0.999f, oB2 = 1.0f - 0.999f;
    const float LR = 0.02f, EPSc = 1e-8f;

    for (int t = 0; t < T; ++t) {
        const float chla = expf(ch0v);
        const float nap  = expf(ch1v);
        const float cdom = expf(ch2v);

        // prior term gradient
        const float d0 = ch0v - xa0, d1 = ch1v - xa1, d2 = ch2v - xa2;
        float g0 = Sa[0][0]*d0 + Sa[0][1]*d1 + Sa[0][2]*d2;
        float g1 = Sa[1][0]*d0 + Sa[1][1]*d1 + Sa[1][2]*d2;
        float g2 = Sa[2][0]*d0 + Sa[2][1]*d1 + Sa[2][2]*d2;

        float r[5], J0[5], J1[5], J2[5];
#pragma unroll
        for (int l = 0; l < 5; ++l) {
            const float da0 = Aph[l] * chla;           // da/dch0
            const float db0 = Bph[l] * chla;           // dbb/dch0
            const float da1 = Anap * nap;              // da/dch1
            const float db1 = Bnap * nap;              // dbb/dch1
            const float da2 = Acd[l] * cdom;           // da/dch2
            const float a   = A0  + da0 + da2 + da1;
            const float bb  = Bb0 + db0 + db1;
            const float s     = a + bb;
            const float inv_s = 1.0f / s;
            const float u     = bb * inv_s;
            const float rrs   = (c1 + c2 * u) * u;
            r[l] = rrs * E[l] - Yv[l];
            const float w = (c1 + 2.0f * c2 * u) * E[l] * inv_s * inv_s;
            J0[l] = w * (db0 * a - da0 * bb);
            J1[l] = w * (db1 * a - da1 * bb);
            J2[l] = w * (-da2 * bb);
        }

        // g += J^T (Sym(Se) r)
#pragma unroll
        for (int i = 0; i < 5; ++i) {
            const float q = Se[i][0]*r[0] + Se[i][1]*r[1] + Se[i][2]*r[2]
                          + Se[i][3]*r[3] + Se[i][4]*r[4];
            g0 += J0[i] * q;
            g1 += J1[i] * q;
            g2 += J2[i] * q;
        }

        // Adam
        p1 *= B1c; p2 *= B2c;
        m0 = B1c*m0 + oB1*g0;  m1 = B1c*m1 + oB1*g1;  m2 = B1c*m2 + oB1*g2;
        v0 = B2c*v0 + oB2*g0*g0;  v1 = B2c*v1 + oB2*g1*g1;  v2 = B2c*v2 + oB2*g2*g2;
        const float im = 1.0f / (1.0f - p1);
        const float iv = 1.0f / (1.0f - p2);
        ch0v -= LR * (m0 * im) / (sqrtf(v0 * iv) + EPSc);
        ch1v -= LR * (m1 * im) / (sqrtf(v1 * iv) + EPSc);
        ch2v -= LR * (m2 * im) / (sqrtf(v2 * iv) + EPSc);
    }

    // Epilogue: kd + bbp from final ch.
    const float chla = expf(ch0v);
    const float nap  = expf(ch1v);
    const float cdom = expf(ch2v);
    const float kdscale = pfv[9] * 0.9f + pfv[10] * 0.1f;

    float o[9];
    o[0] = ch0v;
#pragma unroll
    for (int l = 0; l < 5; ++l) {
        const float a  = A0  + Aph[l]*chla + Acd[l]*cdom + Anap*nap;
        const float bb = Bb0 + Bph[l]*chla + Bnap*nap;
        const float sig = 1.0f / (1.0f + expf(-x3[l]));
        const float mu  = 0.5f + 0.5f * sig;
        o[1 + l] = (a + bb) / mu * kdscale;
    }
    const float lam3[3] = {0.025f, 0.5f, 1.15f};
#pragma unroll
    for (int j = 0; j < 3; ++j) {
        const float bph = pfv[3] * 0.001f * (1.0f + pfv[4] * 0.05f * lam3[j]);
        o[6 + j] = pfv[11] * (bph * chla + Bnap * nap);
    }

#pragma unroll
    for (int i = 0; i < 9; ++i) out[b*9 + i] = o[i];
}

extern "C" void kernel_launch(void* const* d_in, const int* in_sizes, int n_in,
                              void* d_out, int out_size, void* d_ws, size_t ws_size,
                              hipStream_t stream) {
    const float* X   = (const float*)d_in[0];
    const float* Y   = (const float*)d_in[1];
    const float* ch0 = (const float*)d_in[2];
    const float* pf  = (const float*)d_in[3];
    const float* xa  = (const float*)d_in[4];
    const float* sa  = (const float*)d_in[5];
    const float* se  = (const float*)d_in[6];
    const int*   ni  = (const int*)d_in[7];
    float* out = (float*)d_out;

    const int B = in_sizes[0] / 25;
    const int block = 256;
    const int grid = (B + block - 1) / block;
    hipLaunchKernelGGL(pe_kernel, dim3(grid), dim3(block), 0, stream,
                       X, Y, ch0, pf, xa, sa, se, ni, out, B);
}

// Round 2
// 121.399 us; speedup vs baseline: 1.2655x; 1.2655x over previous
//
#include <hip/hip_runtime.h>
#include <math.h>

// One thread per batch element; 50 Adam steps on a 3-parameter problem with
// analytic gradient of the 5-wavelength forward model. All state in registers.
//
// R2 changes vs R1:
//  - native transcendentals: v_exp_f32 (__expf), v_rcp_f32, v_sqrt_f32
//    instead of precise libm expf / fdiv / sqrtf  (~2x dynamic VALU instr cut)
//  - block size 256 -> 64: 1563 blocks over 256 CUs (6-7/CU) instead of
//    391 (1-2/CU, ~2x tail imbalance)

__device__ __forceinline__ float frcp(float x)  { return __builtin_amdgcn_rcpf(x); }
__device__ __forceinline__ float fsqrt_(float x){ return __builtin_amdgcn_sqrtf(x); }
__device__ __forceinline__ float fexp(float x)  { return __expf(x); }

__global__ __launch_bounds__(64)
void pe_kernel(const float* __restrict__ X,      // (B,5,5)
               const float* __restrict__ Y,      // (B,5)
               const float* __restrict__ ch0p,   // (B,1,3)
               const float* __restrict__ pf,     // (14,)
               const float* __restrict__ x_a,    // (3,)
               const float* __restrict__ s_a_inv,// (3,3)
               const float* __restrict__ s_e_inv,// (5,5)
               const int*   __restrict__ n_iter, // (1,)
               float* __restrict__ out,          // (B,9)
               int B)
{
    const int b = blockIdx.x * blockDim.x + threadIdx.x;
    if (b >= B) return;

    const float lam[5] = {-0.275f, 0.025f, 0.5f, 0.7f, 1.15f};

    float pfv[14];
#pragma unroll
    for (int i = 0; i < 14; ++i) pfv[i] = pf[i];

    const float xa0 = x_a[0], xa1 = x_a[1], xa2 = x_a[2];

    float Sa[3][3];
#pragma unroll
    for (int i = 0; i < 3; ++i)
#pragma unroll
        for (int j = 0; j < 3; ++j)
            Sa[i][j] = 0.5f * (s_a_inv[i*3+j] + s_a_inv[j*3+i]);

    float Se[5][5];
#pragma unroll
    for (int i = 0; i < 5; ++i)
#pragma unroll
        for (int j = 0; j < 5; ++j)
            Se[i][j] = 0.5f * (s_e_inv[i*5+j] + s_e_inv[j*5+i]);

    const int T = n_iter[0];

    // Iteration-invariant optics constants.
    const float A0   = 0.0045f, Bb0 = 0.0012f;
    const float Anap = pfv[12] * 0.005f;
    const float Bnap = pfv[13] * 0.005f;
    const float c1   = pfv[7] * 0.089f;
    const float c2   = pfv[8] * 0.1245f;
    float Aph[5], Acd[5], Bph[5];
#pragma unroll
    for (int l = 0; l < 5; ++l) {
        Aph[l] = pfv[0] * 0.05f * (1.0f + pfv[1] * 0.1f * lam[l] + pfv[2] * 0.01f);
        Acd[l] = pfv[5] * 0.1f * fexp(-pfv[6] * 1.7f * lam[l]);
        Bph[l] = pfv[3] * 0.001f * (1.0f + pfv[4] * 0.05f * lam[l]);
    }

    // Per-element iteration-invariant data.
    float E[5], Yv[5], x3[5];
#pragma unroll
    for (int l = 0; l < 5; ++l) {
        const float Edir = X[b*25 + l*5 + 0];
        const float Edif = X[b*25 + l*5 + 1];
        x3[l] = X[b*25 + l*5 + 3];
        E[l]  = (Edir + 0.5f * Edif) * frcp(Edir + Edif);
        Yv[l] = Y[b*5 + l];
    }

    float ch0v = ch0p[b*3 + 0];
    float ch1v = ch0p[b*3 + 1];
    float ch2v = ch0p[b*3 + 2];

    float m0 = 0.f, m1 = 0.f, m2 = 0.f;
    float v0 = 0.f, v1 = 0.f, v2 = 0.f;
    float p1 = 1.0f, p2 = 1.0f;   // running b1^t, b2^t

    const float B1c = 0.9f,  oB1 = 1.0f - 0.9f;
    const float B2c = 0.999f, oB2 = 1.0f - 0.999f;
    const float LR = 0.02f, EPSc = 1e-8f;

    for (int t = 0; t < T; ++t) {
        const float chla = fexp(ch0v);
        const float nap  = fexp(ch1v);
        const float cdom = fexp(ch2v);

        // prior term gradient
        const float d0 = ch0v - xa0, d1 = ch1v - xa1, d2 = ch2v - xa2;
        float g0 = Sa[0][0]*d0 + Sa[0][1]*d1 + Sa[0][2]*d2;
        float g1 = Sa[1][0]*d0 + Sa[1][1]*d1 + Sa[1][2]*d2;
        float g2 = Sa[2][0]*d0 + Sa[2][1]*d1 + Sa[2][2]*d2;

        const float da1 = Anap * nap;   // da/dch1 (λ-independent)
        const float db1 = Bnap * nap;   // dbb/dch1 (λ-independent)

        float r[5], J0[5], J1[5], J2[5];
#pragma unroll
        for (int l = 0; l < 5; ++l) {
            const float da0 = Aph[l] * chla;           // da/dch0
            const float db0 = Bph[l] * chla;           // dbb/dch0
            const float da2 = Acd[l] * cdom;           // da/dch2
            const float a   = A0  + da0 + da2 + da1;
            const float bb  = Bb0 + db0 + db1;
            const float s     = a + bb;
            const float inv_s = frcp(s);
            const float u     = bb * inv_s;
            const float rrs   = (c1 + c2 * u) * u;
            r[l] = rrs * E[l] - Yv[l];
            const float w = (c1 + 2.0f * c2 * u) * E[l] * inv_s * inv_s;
            J0[l] = w * (db0 * a - da0 * bb);
            J1[l] = w * (db1 * a - da1 * bb);
            J2[l] = w * (-da2 * bb);
        }

        // g += J^T (Sym(Se) r)
#pragma unroll
        for (int i = 0; i < 5; ++i) {
            const float q = Se[i][0]*r[0] + Se[i][1]*r[1] + Se[i][2]*r[2]
                          + Se[i][3]*r[3] + Se[i][4]*r[4];
            g0 += J0[i] * q;
            g1 += J1[i] * q;
            g2 += J2[i] * q;
        }

        // Adam
        p1 *= B1c; p2 *= B2c;
        m0 = B1c*m0 + oB1*g0;  m1 = B1c*m1 + oB1*g1;  m2 = B1c*m2 + oB1*g2;
        v0 = B2c*v0 + oB2*g0*g0;  v1 = B2c*v1 + oB2*g1*g1;  v2 = B2c*v2 + oB2*g2*g2;
        const float im = frcp(1.0f - p1);
        const float iv = frcp(1.0f - p2);
        ch0v -= LR * (m0 * im) * frcp(fsqrt_(v0 * iv) + EPSc);
        ch1v -= LR * (m1 * im) * frcp(fsqrt_(v1 * iv) + EPSc);
        ch2v -= LR * (m2 * im) * frcp(fsqrt_(v2 * iv) + EPSc);
    }

    // Epilogue: kd + bbp from final ch.
    const float chla = fexp(ch0v);
    const float nap  = fexp(ch1v);
    const float cdom = fexp(ch2v);
    const float kdscale = pfv[9] * 0.9f + pfv[10] * 0.1f;

    float o[9];
    o[0] = ch0v;
#pragma unroll
    for (int l = 0; l < 5; ++l) {
        const float a  = A0  + Aph[l]*chla + Acd[l]*cdom + Anap*nap;
        const float bb = Bb0 + Bph[l]*chla + Bnap*nap;
        const float sig = frcp(1.0f + fexp(-x3[l]));
        const float mu  = 0.5f + 0.5f * sig;
        o[1 + l] = (a + bb) * frcp(mu) * kdscale;
    }
    const float lam3[3] = {0.025f, 0.5f, 1.15f};
#pragma unroll
    for (int j = 0; j < 3; ++j) {
        const float bph = pfv[3] * 0.001f * (1.0f + pfv[4] * 0.05f * lam3[j]);
        o[6 + j] = pfv[11] * (bph * chla + Bnap * nap);
    }

#pragma unroll
    for (int i = 0; i < 9; ++i) out[b*9 + i] = o[i];
}

extern "C" void kernel_launch(void* const* d_in, const int* in_sizes, int n_in,
                              void* d_out, int out_size, void* d_ws, size_t ws_size,
                              hipStream_t stream) {
    const float* X   = (const float*)d_in[0];
    const float* Y   = (const float*)d_in[1];
    const float* ch0 = (const float*)d_in[2];
    const float* pf  = (const float*)d_in[3];
    const float* xa  = (const float*)d_in[4];
    const float* sa  = (const float*)d_in[5];
    const float* se  = (const float*)d_in[6];
    const int*   ni  = (const int*)d_in[7];
    float* out = (float*)d_out;

    const int B = in_sizes[0] / 25;
    const int block = 64;
    const int grid = (B + block - 1) / block;
    hipLaunchKernelGGL(pe_kernel, dim3(grid), dim3(block), 0, stream,
                       X, Y, ch0, pf, xa, sa, se, ni, out, B);
}

// Round 3
// 114.036 us; speedup vs baseline: 1.3472x; 1.0646x over previous
//
#include <hip/hip_runtime.h>
#include <math.h>

// One thread per TWO batch elements (ILP=2); 50 Adam steps on a 3-parameter
// problem with analytic gradient of the 5-wavelength forward model.
//
// R3 changes vs R2:
//  - 2 elements/thread: 782 waves -> <=1 wave/SIMD, two independent chains
//    statically interleaved by the compiler (beats HW 2-wave arbitration
//    measured at ~40-70% issue efficiency).
//  - Jacobian columns factored: J0 = chla*w.(Bph*a - Aph*bb), etc. (~20
//    fewer ops/iter); Adam bias-correction scalars (rcp(1-b1^t), sqrt of
//    rcp(1-b2^t), LR*im) computed once per iteration, shared by both elems.

__device__ __forceinline__ float frcp(float x)  { return __builtin_amdgcn_rcpf(x); }
__device__ __forceinline__ float fsqrt_(float x){ return __builtin_amdgcn_sqrtf(x); }
__device__ __forceinline__ float fexp(float x)  { return __expf(x); }

__global__ __launch_bounds__(64)
void pe_kernel(const float* __restrict__ X,      // (B,5,5)
               const float* __restrict__ Y,      // (B,5)
               const float* __restrict__ ch0p,   // (B,1,3)
               const float* __restrict__ pf,     // (14,)
               const float* __restrict__ x_a,    // (3,)
               const float* __restrict__ s_a_inv,// (3,3)
               const float* __restrict__ s_e_inv,// (5,5)
               const int*   __restrict__ n_iter, // (1,)
               float* __restrict__ out,          // (B,9)
               int B, int n0)                    // n0 = ceil(B/2)
{
    const int b = blockIdx.x * blockDim.x + threadIdx.x;
    if (b >= n0) return;

    const bool valid1 = (b + n0) < B;
    const int e[2] = { b, valid1 ? (b + n0) : b };

    const float lam[5] = {-0.275f, 0.025f, 0.5f, 0.7f, 1.15f};

    float pfv[14];
#pragma unroll
    for (int i = 0; i < 14; ++i) pfv[i] = pf[i];

    const float xa0 = x_a[0], xa1 = x_a[1], xa2 = x_a[2];

    float Sa[3][3];
#pragma unroll
    for (int i = 0; i < 3; ++i)
#pragma unroll
        for (int j = 0; j < 3; ++j)
            Sa[i][j] = 0.5f * (s_a_inv[i*3+j] + s_a_inv[j*3+i]);

    float Se[5][5];
#pragma unroll
    for (int i = 0; i < 5; ++i)
#pragma unroll
        for (int j = 0; j < 5; ++j)
            Se[i][j] = 0.5f * (s_e_inv[i*5+j] + s_e_inv[j*5+i]);

    const int T = n_iter[0];

    // Iteration-invariant optics constants (uniform).
    const float A0   = 0.0045f, Bb0 = 0.0012f;
    const float Anap = pfv[12] * 0.005f;
    const float Bnap = pfv[13] * 0.005f;
    const float c1   = pfv[7] * 0.089f;
    const float c2   = pfv[8] * 0.1245f;
    const float c22  = 2.0f * c2;
    float Aph[5], Acd[5], Bph[5];
#pragma unroll
    for (int l = 0; l < 5; ++l) {
        Aph[l] = pfv[0] * 0.05f * (1.0f + pfv[1] * 0.1f * lam[l] + pfv[2] * 0.01f);
        Acd[l] = pfv[5] * 0.1f * fexp(-pfv[6] * 1.7f * lam[l]);
        Bph[l] = pfv[3] * 0.001f * (1.0f + pfv[4] * 0.05f * lam[l]);
    }

    // Per-element iteration-invariant data.
    float E[2][5], Yv[2][5], x3[2][5];
#pragma unroll
    for (int ee = 0; ee < 2; ++ee)
#pragma unroll
        for (int l = 0; l < 5; ++l) {
            const float Edir = X[e[ee]*25 + l*5 + 0];
            const float Edif = X[e[ee]*25 + l*5 + 1];
            x3[ee][l] = X[e[ee]*25 + l*5 + 3];
            E[ee][l]  = (Edir + 0.5f * Edif) * frcp(Edir + Edif);
            Yv[ee][l] = Y[e[ee]*5 + l];
        }

    float ch[2][3], mm[2][3], vv[2][3];
#pragma unroll
    for (int ee = 0; ee < 2; ++ee)
#pragma unroll
        for (int k = 0; k < 3; ++k) {
            ch[ee][k] = ch0p[e[ee]*3 + k];
            mm[ee][k] = 0.f;
            vv[ee][k] = 0.f;
        }

    float p1 = 1.0f, p2 = 1.0f;
    const float B1c = 0.9f,  oB1 = 1.0f - 0.9f;
    const float B2c = 0.999f, oB2 = 1.0f - 0.999f;
    const float LR = 0.02f, EPSc = 1e-8f;

    for (int t = 0; t < T; ++t) {
        // Per-iteration uniform Adam scalars (shared by both elements).
        p1 *= B1c; p2 *= B2c;
        const float im   = frcp(1.0f - p1);
        const float iv   = frcp(1.0f - p2);
        const float sqiv = fsqrt_(iv);
        const float lrim = LR * im;

#pragma unroll
        for (int ee = 0; ee < 2; ++ee) {
            const float chla = fexp(ch[ee][0]);
            const float nap  = fexp(ch[ee][1]);
            const float cdom = fexp(ch[ee][2]);

            // prior-term gradient
            const float d0 = ch[ee][0] - xa0, d1 = ch[ee][1] - xa1, d2 = ch[ee][2] - xa2;
            float g0 = Sa[0][0]*d0 + Sa[0][1]*d1 + Sa[0][2]*d2;
            float g1 = Sa[1][0]*d0 + Sa[1][1]*d1 + Sa[1][2]*d2;
            float g2 = Sa[2][0]*d0 + Sa[2][1]*d1 + Sa[2][2]*d2;

            const float da1 = Anap * nap;
            const float db1 = Bnap * nap;

            // pass 1: per-lambda optics, residual, weight
            float av[5], bv[5], wv[5], rv[5];
#pragma unroll
            for (int l = 0; l < 5; ++l) {
                const float da0 = Aph[l] * chla;
                const float db0 = Bph[l] * chla;
                const float da2 = Acd[l] * cdom;
                const float a   = A0  + da0 + da2 + da1;
                const float bb  = Bb0 + db0 + db1;
                const float inv_s = frcp(a + bb);
                const float u     = bb * inv_s;
                const float rrs   = (c1 + c2 * u) * u;
                av[l] = a;
                bv[l] = bb;
                rv[l] = rrs * E[ee][l] - Yv[ee][l];
                wv[l] = (c1 + c22 * u) * E[ee][l] * inv_s * inv_s;
            }

            // pass 2: g += [chla,nap,cdom-factored] J^T (Sym(Se) r)
            float s0 = 0.f, s1 = 0.f, s2 = 0.f;
#pragma unroll
            for (int i = 0; i < 5; ++i) {
                const float q = Se[i][0]*rv[0] + Se[i][1]*rv[1] + Se[i][2]*rv[2]
                              + Se[i][3]*rv[3] + Se[i][4]*rv[4];
                const float h = wv[i] * q;
                s0 += h * (Bph[i] * av[i] - Aph[i] * bv[i]);
                s1 += h * (Bnap   * av[i] - Anap   * bv[i]);
                s2 += h * (Acd[i] * bv[i]);
            }
            g0 += chla * s0;
            g1 += nap  * s1;
            g2 -= cdom * s2;

            // Adam update
            const float gs[3] = {g0, g1, g2};
#pragma unroll
            for (int k = 0; k < 3; ++k) {
                const float g = gs[k];
                mm[ee][k] = B1c * mm[ee][k] + oB1 * g;
                vv[ee][k] = B2c * vv[ee][k] + oB2 * (g * g);
                const float den = fsqrt_(vv[ee][k]) * sqiv + EPSc;
                ch[ee][k] -= (lrim * mm[ee][k]) * frcp(den);
            }
        }
    }

    // Epilogue
    const float kdscale = pfv[9] * 0.9f + pfv[10] * 0.1f;
    const float lam3[3] = {0.025f, 0.5f, 1.15f};

#pragma unroll
    for (int ee = 0; ee < 2; ++ee) {
        if (ee == 1 && !valid1) break;
        const float chla = fexp(ch[ee][0]);
        const float nap  = fexp(ch[ee][1]);
        const float cdom = fexp(ch[ee][2]);

        float o[9];
        o[0] = ch[ee][0];
#pragma unroll
        for (int l = 0; l < 5; ++l) {
            const float a  = A0  + Aph[l]*chla + Acd[l]*cdom + Anap*nap;
            const float bb = Bb0 + Bph[l]*chla + Bnap*nap;
            const float sig = frcp(1.0f + fexp(-x3[ee][l]));
            const float mu  = 0.5f + 0.5f * sig;
            o[1 + l] = (a + bb) * frcp(mu) * kdscale;
        }
#pragma unroll
        for (int j = 0; j < 3; ++j) {
            const float bph = pfv[3] * 0.001f * (1.0f + pfv[4] * 0.05f * lam3[j]);
            o[6 + j] = pfv[11] * (bph * chla + Bnap * nap);
        }
#pragma unroll
        for (int i = 0; i < 9; ++i) out[e[ee]*9 + i] = o[i];
    }
}

extern "C" void kernel_launch(void* const* d_in, const int* in_sizes, int n_in,
                              void* d_out, int out_size, void* d_ws, size_t ws_size,
                              hipStream_t stream) {
    const float* X   = (const float*)d_in[0];
    const float* Y   = (const float*)d_in[1];
    const float* ch0 = (const float*)d_in[2];
    const float* pf  = (const float*)d_in[3];
    const float* xa  = (const float*)d_in[4];
    const float* sa  = (const float*)d_in[5];
    const float* se  = (const float*)d_in[6];
    const int*   ni  = (const int*)d_in[7];
    float* out = (float*)d_out;

    const int B  = in_sizes[0] / 25;
    const int n0 = (B + 1) / 2;
    const int block = 64;
    const int grid = (n0 + block - 1) / block;
    hipLaunchKernelGGL(pe_kernel, dim3(grid), dim3(block), 0, stream,
                       X, Y, ch0, pf, xa, sa, se, ni, out, B, n0);
}

// Round 4
// 102.607 us; speedup vs baseline: 1.4973x; 1.1114x over previous
//
#include <hip/hip_runtime.h>
#include <math.h>

// One thread per TWO batch elements, processed as a PACKED float2 pair so the
// compiler emits v_pk_fma_f32 / v_pk_mul_f32 / v_pk_add_f32 (CDNA full-rate
// packed FP32: 2 FMAs/lane per 2-cycle issue slot -> halves issue slots and
// VALU pipe cycles for the FMA-dominated body).
// Transcendentals (exp/rcp/sqrt) stay scalar per component.

typedef float v2f __attribute__((ext_vector_type(2)));

__device__ __forceinline__ float frcp(float x)  { return __builtin_amdgcn_rcpf(x); }
__device__ __forceinline__ float fsqrt_(float x){ return __builtin_amdgcn_sqrtf(x); }
__device__ __forceinline__ float fexp(float x)  { return __expf(x); }

__device__ __forceinline__ v2f vexp(v2f x){ v2f r; r.x = fexp(x.x); r.y = fexp(x.y); return r; }
__device__ __forceinline__ v2f vrcp(v2f x){ v2f r; r.x = frcp(x.x); r.y = frcp(x.y); return r; }
__device__ __forceinline__ v2f vsqrt(v2f x){ v2f r; r.x = fsqrt_(x.x); r.y = fsqrt_(x.y); return r; }

__global__ __launch_bounds__(64)
void pe_kernel(const float* __restrict__ X,      // (B,5,5)
               const float* __restrict__ Y,      // (B,5)
               const float* __restrict__ ch0p,   // (B,1,3)
               const float* __restrict__ pf,     // (14,)
               const float* __restrict__ x_a,    // (3,)
               const float* __restrict__ s_a_inv,// (3,3)
               const float* __restrict__ s_e_inv,// (5,5)
               const int*   __restrict__ n_iter, // (1,)
               float* __restrict__ out,          // (B,9)
               int B, int n0)                    // n0 = ceil(B/2)
{
    const int b = blockIdx.x * blockDim.x + threadIdx.x;
    if (b >= n0) return;

    const bool valid1 = (b + n0) < B;
    const int e0 = b;
    const int e1 = valid1 ? (b + n0) : b;

    const float lam[5] = {-0.275f, 0.025f, 0.5f, 0.7f, 1.15f};

    float pfv[14];
#pragma unroll
    for (int i = 0; i < 14; ++i) pfv[i] = pf[i];

    const float xa0 = x_a[0], xa1 = x_a[1], xa2 = x_a[2];

    float Sa[3][3];
#pragma unroll
    for (int i = 0; i < 3; ++i)
#pragma unroll
        for (int j = 0; j < 3; ++j)
            Sa[i][j] = 0.5f * (s_a_inv[i*3+j] + s_a_inv[j*3+i]);

    float Se[5][5];
#pragma unroll
    for (int i = 0; i < 5; ++i)
#pragma unroll
        for (int j = 0; j < 5; ++j)
            Se[i][j] = 0.5f * (s_e_inv[i*5+j] + s_e_inv[j*5+i]);

    const int T = n_iter[0];

    // Iteration-invariant optics constants (uniform scalars -> SGPRs).
    const float A0   = 0.0045f, Bb0 = 0.0012f;
    const float Anap = pfv[12] * 0.005f;
    const float Bnap = pfv[13] * 0.005f;
    const float c1   = pfv[7] * 0.089f;
    const float c2   = pfv[8] * 0.1245f;
    const float c22  = 2.0f * c2;
    float Aph[5], Acd[5], Bph[5];
#pragma unroll
    for (int l = 0; l < 5; ++l) {
        Aph[l] = pfv[0] * 0.05f * (1.0f + pfv[1] * 0.1f * lam[l] + pfv[2] * 0.01f);
        Acd[l] = pfv[5] * 0.1f * fexp(-pfv[6] * 1.7f * lam[l]);
        Bph[l] = pfv[3] * 0.001f * (1.0f + pfv[4] * 0.05f * lam[l]);
    }

    // Per-element iteration-invariant data, packed as (elem0, elem1).
    v2f E[5], Yv[5], x3[5];
#pragma unroll
    for (int l = 0; l < 5; ++l) {
        const float Edir0 = X[e0*25 + l*5 + 0], Edir1 = X[e1*25 + l*5 + 0];
        const float Edif0 = X[e0*25 + l*5 + 1], Edif1 = X[e1*25 + l*5 + 1];
        x3[l].x = X[e0*25 + l*5 + 3];  x3[l].y = X[e1*25 + l*5 + 3];
        E[l].x  = (Edir0 + 0.5f * Edif0) * frcp(Edir0 + Edif0);
        E[l].y  = (Edir1 + 0.5f * Edif1) * frcp(Edir1 + Edif1);
        Yv[l].x = Y[e0*5 + l];  Yv[l].y = Y[e1*5 + l];
    }

    v2f ch[3], mm[3], vv[3];
#pragma unroll
    for (int k = 0; k < 3; ++k) {
        ch[k].x = ch0p[e0*3 + k];
        ch[k].y = ch0p[e1*3 + k];
        mm[k] = (v2f)0.0f;
        vv[k] = (v2f)0.0f;
    }

    float p1 = 1.0f, p2 = 1.0f;
    const float B1c = 0.9f,  oB1 = 1.0f - 0.9f;
    const float B2c = 0.999f, oB2 = 1.0f - 0.999f;
    const float LR = 0.02f, EPSc = 1e-8f;

    for (int t = 0; t < T; ++t) {
        // Per-iteration uniform Adam scalars.
        p1 *= B1c; p2 *= B2c;
        const float im   = frcp(1.0f - p1);
        const float sqiv = fsqrt_(frcp(1.0f - p2));
        const float lrim = LR * im;

        const v2f chla = vexp(ch[0]);
        const v2f nap  = vexp(ch[1]);
        const v2f cdom = vexp(ch[2]);

        // prior-term gradient
        const v2f d0 = ch[0] - xa0, d1 = ch[1] - xa1, d2 = ch[2] - xa2;
        v2f g0 = Sa[0][0]*d0 + Sa[0][1]*d1 + Sa[0][2]*d2;
        v2f g1 = Sa[1][0]*d0 + Sa[1][1]*d1 + Sa[1][2]*d2;
        v2f g2 = Sa[2][0]*d0 + Sa[2][1]*d1 + Sa[2][2]*d2;

        const v2f da1 = Anap * nap;
        const v2f db1 = Bnap * nap;

        // pass 1: per-lambda optics, residual, weight
        v2f av[5], bv[5], wv[5], rv[5];
#pragma unroll
        for (int l = 0; l < 5; ++l) {
            const v2f da0 = Aph[l] * chla;
            const v2f db0 = Bph[l] * chla;
            const v2f da2 = Acd[l] * cdom;
            const v2f a   = A0  + da0 + da2 + da1;
            const v2f bb  = Bb0 + db0 + db1;
            const v2f inv_s = vrcp(a + bb);
            const v2f u     = bb * inv_s;
            const v2f rrs   = (c1 + c2 * u) * u;
            av[l] = a;
            bv[l] = bb;
            rv[l] = rrs * E[l] - Yv[l];
            wv[l] = (c1 + c22 * u) * E[l] * inv_s * inv_s;
        }

        // pass 2: g += [chla,nap,cdom-factored] J^T (Sym(Se) r)
        v2f s0 = (v2f)0.0f, s1 = (v2f)0.0f, s2 = (v2f)0.0f;
#pragma unroll
        for (int i = 0; i < 5; ++i) {
            const v2f q = Se[i][0]*rv[0] + Se[i][1]*rv[1] + Se[i][2]*rv[2]
                        + Se[i][3]*rv[3] + Se[i][4]*rv[4];
            const v2f h = wv[i] * q;
            s0 += h * (Bph[i] * av[i] - Aph[i] * bv[i]);
            s1 += h * (Bnap   * av[i] - Anap   * bv[i]);
            s2 += h * (Acd[i] * bv[i]);
        }
        g0 += chla * s0;
        g1 += nap  * s1;
        g2 -= cdom * s2;

        // Adam update (packed, per-component sqrt/rcp)
        const v2f gs[3] = {g0, g1, g2};
#pragma unroll
        for (int k = 0; k < 3; ++k) {
            const v2f g = gs[k];
            mm[k] = B1c * mm[k] + oB1 * g;
            vv[k] = B2c * vv[k] + oB2 * (g * g);
            const v2f den = vsqrt(vv[k]) * sqiv + EPSc;
            ch[k] -= (lrim * mm[k]) * vrcp(den);
        }
    }

    // Epilogue
    const float kdscale = pfv[9] * 0.9f + pfv[10] * 0.1f;
    const float lam3[3] = {0.025f, 0.5f, 1.15f};

    const v2f chla = vexp(ch[0]);
    const v2f nap  = vexp(ch[1]);
    const v2f cdom = vexp(ch[2]);

#pragma unroll
    for (int ee = 0; ee < 2; ++ee) {
        if (ee == 1 && !valid1) break;
        const int e = ee ? e1 : e0;
        const float chl = ee ? chla.y : chla.x;
        const float np  = ee ? nap.y  : nap.x;
        const float cd  = ee ? cdom.y : cdom.x;

        float o[9];
        o[0] = ee ? ch[0].y : ch[0].x;
#pragma unroll
        for (int l = 0; l < 5; ++l) {
            const float a  = A0  + Aph[l]*chl + Acd[l]*cd + Anap*np;
            const float bb = Bb0 + Bph[l]*chl + Bnap*np;
            const float xx = ee ? x3[l].y : x3[l].x;
            const float sig = frcp(1.0f + fexp(-xx));
            const float mu  = 0.5f + 0.5f * sig;
            o[1 + l] = (a + bb) * frcp(mu) * kdscale;
        }
#pragma unroll
        for (int j = 0; j < 3; ++j) {
            const float bph = pfv[3] * 0.001f * (1.0f + pfv[4] * 0.05f * lam3[j]);
            o[6 + j] = pfv[11] * (bph * chl + Bnap * np);
        }
#pragma unroll
        for (int i = 0; i < 9; ++i) out[e*9 + i] = o[i];
    }
}

extern "C" void kernel_launch(void* const* d_in, const int* in_sizes, int n_in,
                              void* d_out, int out_size, void* d_ws, size_t ws_size,
                              hipStream_t stream) {
    const float* X   = (const float*)d_in[0];
    const float* Y   = (const float*)d_in[1];
    const float* ch0 = (const float*)d_in[2];
    const float* pf  = (const float*)d_in[3];
    const float* xa  = (const float*)d_in[4];
    const float* sa  = (const float*)d_in[5];
    const float* se  = (const float*)d_in[6];
    const int*   ni  = (const int*)d_in[7];
    float* out = (float*)d_out;

    const int B  = in_sizes[0] / 25;
    const int n0 = (B + 1) / 2;
    const int block = 64;
    const int grid = (n0 + block - 1) / block;
    hipLaunchKernelGGL(pe_kernel, dim3(grid), dim3(block), 0, stream,
                       X, Y, ch0, pf, xa, sa, se, ni, out, B, n0);
}

// Round 5
// 98.476 us; speedup vs baseline: 1.5601x; 1.0419x over previous
//
#include <hip/hip_runtime.h>
#include <math.h>

// One thread per TWO batch elements as a packed float2 (v_pk_* fp32).
// R5: runtime wave-uniform fast path for diagonal Sym(S_e)/Sym(S_a)
// (true for the benchmarked inputs: S_e = 1e4*I, S_a = I):
//   q_i = SeD_i * r_i  ->  fold SeD*E into per-lambda constant ES[l];
//   prior matvec -> 3 muls; fused single-pass lambda loop (no staging
//   arrays); s1 column factored via ha=sum(h*a), hb=sum(h*bb).
// General dense path kept as fallback.

typedef float v2f __attribute__((ext_vector_type(2)));

__device__ __forceinline__ float frcp(float x)  { return __builtin_amdgcn_rcpf(x); }
__device__ __forceinline__ float fsqrt_(float x){ return __builtin_amdgcn_sqrtf(x); }
__device__ __forceinline__ float fexp(float x)  { return __expf(x); }

__device__ __forceinline__ v2f vexp(v2f x){ v2f r; r.x = fexp(x.x); r.y = fexp(x.y); return r; }
__device__ __forceinline__ v2f vrcp(v2f x){ v2f r; r.x = frcp(x.x); r.y = frcp(x.y); return r; }
__device__ __forceinline__ v2f vsqrt(v2f x){ v2f r; r.x = fsqrt_(x.x); r.y = fsqrt_(x.y); return r; }

__global__ __launch_bounds__(64)
void pe_kernel(const float* __restrict__ X,      // (B,5,5)
               const float* __restrict__ Y,      // (B,5)
               const float* __restrict__ ch0p,   // (B,1,3)
               const float* __restrict__ pf,     // (14,)
               const float* __restrict__ x_a,    // (3,)
               const float* __restrict__ s_a_inv,// (3,3)
               const float* __restrict__ s_e_inv,// (5,5)
               const int*   __restrict__ n_iter, // (1,)
               float* __restrict__ out,          // (B,9)
               int B, int n0)                    // n0 = ceil(B/2)
{
    const int b = blockIdx.x * blockDim.x + threadIdx.x;
    if (b >= n0) return;

    const bool valid1 = (b + n0) < B;
    const int e0 = b;
    const int e1 = valid1 ? (b + n0) : b;

    const float lam[5] = {-0.275f, 0.025f, 0.5f, 0.7f, 1.15f};

    float pfv[14];
#pragma unroll
    for (int i = 0; i < 14; ++i) pfv[i] = pf[i];

    const float xa0 = x_a[0], xa1 = x_a[1], xa2 = x_a[2];

    float Sa[3][3];
#pragma unroll
    for (int i = 0; i < 3; ++i)
#pragma unroll
        for (int j = 0; j < 3; ++j)
            Sa[i][j] = 0.5f * (s_a_inv[i*3+j] + s_a_inv[j*3+i]);

    float Se[5][5];
#pragma unroll
    for (int i = 0; i < 5; ++i)
#pragma unroll
        for (int j = 0; j < 5; ++j)
            Se[i][j] = 0.5f * (s_e_inv[i*5+j] + s_e_inv[j*5+i]);

    // Wave-uniform structure check (all threads agree; branch is free).
    bool diag = true;
#pragma unroll
    for (int i = 0; i < 5; ++i)
#pragma unroll
        for (int j = 0; j < 5; ++j)
            if (i != j && Se[i][j] != 0.0f) diag = false;
#pragma unroll
    for (int i = 0; i < 3; ++i)
#pragma unroll
        for (int j = 0; j < 3; ++j)
            if (i != j && Sa[i][j] != 0.0f) diag = false;

    const int T = n_iter[0];

    // Iteration-invariant optics constants (uniform).
    const float A0   = 0.0045f, Bb0 = 0.0012f;
    const float Anap = pfv[12] * 0.005f;
    const float Bnap = pfv[13] * 0.005f;
    const float c1   = pfv[7] * 0.089f;
    const float c2   = pfv[8] * 0.1245f;
    const float c22  = 2.0f * c2;
    float Aph[5], Acd[5], Bph[5];
#pragma unroll
    for (int l = 0; l < 5; ++l) {
        Aph[l] = pfv[0] * 0.05f * (1.0f + pfv[1] * 0.1f * lam[l] + pfv[2] * 0.01f);
        Acd[l] = pfv[5] * 0.1f * fexp(-pfv[6] * 1.7f * lam[l]);
        Bph[l] = pfv[3] * 0.001f * (1.0f + pfv[4] * 0.05f * lam[l]);
    }

    // Per-element iteration-invariant data, packed (elem0, elem1).
    v2f E[5], Yv[5], x3[5];
#pragma unroll
    for (int l = 0; l < 5; ++l) {
        const float Edir0 = X[e0*25 + l*5 + 0], Edir1 = X[e1*25 + l*5 + 0];
        const float Edif0 = X[e0*25 + l*5 + 1], Edif1 = X[e1*25 + l*5 + 1];
        x3[l].x = X[e0*25 + l*5 + 3];  x3[l].y = X[e1*25 + l*5 + 3];
        E[l].x  = (Edir0 + 0.5f * Edif0) * frcp(Edir0 + Edif0);
        E[l].y  = (Edir1 + 0.5f * Edif1) * frcp(Edir1 + Edif1);
        Yv[l].x = Y[e0*5 + l];  Yv[l].y = Y[e1*5 + l];
    }

    v2f ch[3], mm[3], vv[3];
#pragma unroll
    for (int k = 0; k < 3; ++k) {
        ch[k].x = ch0p[e0*3 + k];
        ch[k].y = ch0p[e1*3 + k];
        mm[k] = (v2f)0.0f;
        vv[k] = (v2f)0.0f;
    }

    float p1 = 1.0f, p2 = 1.0f;
    const float B1c = 0.9f,  oB1 = 1.0f - 0.9f;
    const float B2c = 0.999f, oB2 = 1.0f - 0.999f;
    const float LR = 0.02f, EPSc = 1e-8f;

    if (diag) {
        // ---------- fast path: diagonal Sym(Se), Sym(Sa) ----------
        const float SaD0 = Sa[0][0], SaD1 = Sa[1][1], SaD2 = Sa[2][2];
        v2f ES[5];
#pragma unroll
        for (int l = 0; l < 5; ++l) ES[l] = Se[l][l] * E[l];

        for (int t = 0; t < T; ++t) {
            p1 *= B1c; p2 *= B2c;
            const float im   = frcp(1.0f - p1);
            const float sqiv = fsqrt_(frcp(1.0f - p2));
            const float lrim = LR * im;

            const v2f chla = vexp(ch[0]);
            const v2f nap  = vexp(ch[1]);
            const v2f cdom = vexp(ch[2]);

            const v2f at = A0  + Anap * nap;   // shared across lambda
            const v2f bt = Bb0 + Bnap * nap;

            v2f s0 = (v2f)0.0f, s2 = (v2f)0.0f;
            v2f ha = (v2f)0.0f, hb = (v2f)0.0f;
#pragma unroll
            for (int l = 0; l < 5; ++l) {
                const v2f a   = Aph[l] * chla + (Acd[l] * cdom + at);
                const v2f bb  = Bph[l] * chla + bt;
                const v2f inv = vrcp(a + bb);
                const v2f u   = bb * inv;
                const v2f t1  = c1 + c2 * u;          // c1 + c2 u
                const v2f r   = (t1 * u) * E[l] - Yv[l];
                const v2f w2  = t1 + c2 * u;          // c1 + 2 c2 u
                const v2f h   = (w2 * (inv * inv)) * (ES[l] * r);
                s0 += h * (Bph[l] * a - Aph[l] * bb);
                ha += h * a;
                hb += h * bb;
                s2 += (h * Acd[l]) * bb;
            }
            const v2f s1 = Bnap * ha - Anap * hb;

            v2f gs[3];
            gs[0] = SaD0 * (ch[0] - xa0) + chla * s0;
            gs[1] = SaD1 * (ch[1] - xa1) + nap  * s1;
            gs[2] = SaD2 * (ch[2] - xa2) - cdom * s2;

#pragma unroll
            for (int k = 0; k < 3; ++k) {
                const v2f g = gs[k];
                mm[k] = B1c * mm[k] + oB1 * g;
                vv[k] = B2c * vv[k] + oB2 * (g * g);
                const v2f den = vsqrt(vv[k]) * sqiv + EPSc;
                ch[k] -= (lrim * mm[k]) * vrcp(den);
            }
        }
    } else {
        // ---------- general path (dense Sym(Se)/Sym(Sa)) ----------
        for (int t = 0; t < T; ++t) {
            p1 *= B1c; p2 *= B2c;
            const float im   = frcp(1.0f - p1);
            const float sqiv = fsqrt_(frcp(1.0f - p2));
            const float lrim = LR * im;

            const v2f chla = vexp(ch[0]);
            const v2f nap  = vexp(ch[1]);
            const v2f cdom = vexp(ch[2]);

            const v2f d0 = ch[0] - xa0, d1 = ch[1] - xa1, d2 = ch[2] - xa2;
            v2f g0 = Sa[0][0]*d0 + Sa[0][1]*d1 + Sa[0][2]*d2;
            v2f g1 = Sa[1][0]*d0 + Sa[1][1]*d1 + Sa[1][2]*d2;
            v2f g2 = Sa[2][0]*d0 + Sa[2][1]*d1 + Sa[2][2]*d2;

            const v2f da1 = Anap * nap;
            const v2f db1 = Bnap * nap;

            v2f av[5], bv[5], wv[5], rv[5];
#pragma unroll
            for (int l = 0; l < 5; ++l) {
                const v2f da0 = Aph[l] * chla;
                const v2f db0 = Bph[l] * chla;
                const v2f da2 = Acd[l] * cdom;
                const v2f a   = A0  + da0 + da2 + da1;
                const v2f bb  = Bb0 + db0 + db1;
                const v2f inv_s = vrcp(a + bb);
                const v2f u     = bb * inv_s;
                const v2f rrs   = (c1 + c2 * u) * u;
                av[l] = a;
                bv[l] = bb;
                rv[l] = rrs * E[l] - Yv[l];
                wv[l] = (c1 + c22 * u) * E[l] * inv_s * inv_s;
            }

            v2f s0 = (v2f)0.0f, s1 = (v2f)0.0f, s2 = (v2f)0.0f;
#pragma unroll
            for (int i = 0; i < 5; ++i) {
                const v2f q = Se[i][0]*rv[0] + Se[i][1]*rv[1] + Se[i][2]*rv[2]
                            + Se[i][3]*rv[3] + Se[i][4]*rv[4];
                const v2f h = wv[i] * q;
                s0 += h * (Bph[i] * av[i] - Aph[i] * bv[i]);
                s1 += h * (Bnap   * av[i] - Anap   * bv[i]);
                s2 += h * (Acd[i] * bv[i]);
            }
            g0 += chla * s0;
            g1 += nap  * s1;
            g2 -= cdom * s2;

            const v2f gs[3] = {g0, g1, g2};
#pragma unroll
            for (int k = 0; k < 3; ++k) {
                const v2f g = gs[k];
                mm[k] = B1c * mm[k] + oB1 * g;
                vv[k] = B2c * vv[k] + oB2 * (g * g);
                const v2f den = vsqrt(vv[k]) * sqiv + EPSc;
                ch[k] -= (lrim * mm[k]) * vrcp(den);
            }
        }
    }

    // Epilogue
    const float kdscale = pfv[9] * 0.9f + pfv[10] * 0.1f;
    const float lam3[3] = {0.025f, 0.5f, 1.15f};

    const v2f chla = vexp(ch[0]);
    const v2f nap  = vexp(ch[1]);
    const v2f cdom = vexp(ch[2]);

#pragma unroll
    for (int ee = 0; ee < 2; ++ee) {
        if (ee == 1 && !valid1) break;
        const int e = ee ? e1 : e0;
        const float chl = ee ? chla.y : chla.x;
        const float np  = ee ? nap.y  : nap.x;
        const float cd  = ee ? cdom.y : cdom.x;

        float o[9];
        o[0] = ee ? ch[0].y : ch[0].x;
#pragma unroll
        for (int l = 0; l < 5; ++l) {
            const float a  = A0  + Aph[l]*chl + Acd[l]*cd + Anap*np;
            const float bb = Bb0 + Bph[l]*chl + Bnap*np;
            const float xx = ee ? x3[l].y : x3[l].x;
            const float sig = frcp(1.0f + fexp(-xx));
            const float mu  = 0.5f + 0.5f * sig;
            o[1 + l] = (a + bb) * frcp(mu) * kdscale;
        }
#pragma unroll
        for (int j = 0; j < 3; ++j) {
            const float bph = pfv[3] * 0.001f * (1.0f + pfv[4] * 0.05f * lam3[j]);
            o[6 + j] = pfv[11] * (bph * chl + Bnap * np);
        }
#pragma unroll
        for (int i = 0; i < 9; ++i) out[e*9 + i] = o[i];
    }
}

extern "C" void kernel_launch(void* const* d_in, const int* in_sizes, int n_in,
                              void* d_out, int out_size, void* d_ws, size_t ws_size,
                              hipStream_t stream) {
    const float* X   = (const float*)d_in[0];
    const float* Y   = (const float*)d_in[1];
    const float* ch0 = (const float*)d_in[2];
    const float* pf  = (const float*)d_in[3];
    const float* xa  = (const float*)d_in[4];
    const float* sa  = (const float*)d_in[5];
    const float* se  = (const float*)d_in[6];
    const int*   ni  = (const int*)d_in[7];
    float* out = (float*)d_out;

    const int B  = in_sizes[0] / 25;
    const int n0 = (B + 1) / 2;
    const int block = 64;
    const int grid = (n0 + block - 1) / block;
    hipLaunchKernelGGL(pe_kernel, dim3(grid), dim3(block), 0, stream,
                       X, Y, ch0, pf, xa, sa, se, ni, out, B, n0);
}

// Round 6
// 97.436 us; speedup vs baseline: 1.5767x; 1.0107x over previous
//
#include <hip/hip_runtime.h>
#include <math.h>

// One thread per TWO batch elements as a packed float2 (v_pk_* fp32).
// R6: shorter per-iteration dependency chain in the diagonal fast path:
//  - u-factored Jacobian: (Bph*a - Aph*bb)*p^2 = p*(Bph - AB*u); h*a = k*(1-u),
//    h*bb = k*u with k = w2*p*ESr  (a and inv^2 leave the chain)
//  - residual fold: ES*(rrs*E - Yv) = rrs*E2S - YES, E2S = Se*E^2, YES = Se*E*Yv
//  - even/odd dual accumulators (halve the serial reduction depth)
//  - all per-lambda constants pre-broadcast to v2f (pure v2f x v2f ops)
// General dense path kept as fallback.

typedef float v2f __attribute__((ext_vector_type(2)));

__device__ __forceinline__ float frcp(float x)  { return __builtin_amdgcn_rcpf(x); }
__device__ __forceinline__ float fsqrt_(float x){ return __builtin_amdgcn_sqrtf(x); }
__device__ __forceinline__ float fexp(float x)  { return __expf(x); }

__device__ __forceinline__ v2f vexp(v2f x){ v2f r; r.x = fexp(x.x); r.y = fexp(x.y); return r; }
__device__ __forceinline__ v2f vrcp(v2f x){ v2f r; r.x = frcp(x.x); r.y = frcp(x.y); return r; }
__device__ __forceinline__ v2f vsqrt(v2f x){ v2f r; r.x = fsqrt_(x.x); r.y = fsqrt_(x.y); return r; }
__device__ __forceinline__ v2f bcast(float x){ v2f r; r.x = x; r.y = x; return r; }

__global__ __launch_bounds__(64)
void pe_kernel(const float* __restrict__ X,      // (B,5,5)
               const float* __restrict__ Y,      // (B,5)
               const float* __restrict__ ch0p,   // (B,1,3)
               const float* __restrict__ pf,     // (14,)
               const float* __restrict__ x_a,    // (3,)
               const float* __restrict__ s_a_inv,// (3,3)
               const float* __restrict__ s_e_inv,// (5,5)
               const int*   __restrict__ n_iter, // (1,)
               float* __restrict__ out,          // (B,9)
               int B, int n0)                    // n0 = ceil(B/2)
{
    const int b = blockIdx.x * blockDim.x + threadIdx.x;
    if (b >= n0) return;

    const bool valid1 = (b + n0) < B;
    const int e0 = b;
    const int e1 = valid1 ? (b + n0) : b;

    const float lam[5] = {-0.275f, 0.025f, 0.5f, 0.7f, 1.15f};

    float pfv[14];
#pragma unroll
    for (int i = 0; i < 14; ++i) pfv[i] = pf[i];

    const float xa0 = x_a[0], xa1 = x_a[1], xa2 = x_a[2];

    float Sa[3][3];
#pragma unroll
    for (int i = 0; i < 3; ++i)
#pragma unroll
        for (int j = 0; j < 3; ++j)
            Sa[i][j] = 0.5f * (s_a_inv[i*3+j] + s_a_inv[j*3+i]);

    float Se[5][5];
#pragma unroll
    for (int i = 0; i < 5; ++i)
#pragma unroll
        for (int j = 0; j < 5; ++j)
            Se[i][j] = 0.5f * (s_e_inv[i*5+j] + s_e_inv[j*5+i]);

    // Wave-uniform structure check.
    bool diag = true;
#pragma unroll
    for (int i = 0; i < 5; ++i)
#pragma unroll
        for (int j = 0; j < 5; ++j)
            if (i != j && Se[i][j] != 0.0f) diag = false;
#pragma unroll
    for (int i = 0; i < 3; ++i)
#pragma unroll
        for (int j = 0; j < 3; ++j)
            if (i != j && Sa[i][j] != 0.0f) diag = false;

    const int T = n_iter[0];

    // Iteration-invariant optics constants (uniform).
    const float A0   = 0.0045f, Bb0 = 0.0012f;
    const float Anap = pfv[12] * 0.005f;
    const float Bnap = pfv[13] * 0.005f;
    const float c1   = pfv[7] * 0.089f;
    const float c2   = pfv[8] * 0.1245f;
    const float c22  = 2.0f * c2;
    float Aph[5], Acd[5], Bph[5];
#pragma unroll
    for (int l = 0; l < 5; ++l) {
        Aph[l] = pfv[0] * 0.05f * (1.0f + pfv[1] * 0.1f * lam[l] + pfv[2] * 0.01f);
        Acd[l] = pfv[5] * 0.1f * fexp(-pfv[6] * 1.7f * lam[l]);
        Bph[l] = pfv[3] * 0.001f * (1.0f + pfv[4] * 0.05f * lam[l]);
    }

    // Per-element iteration-invariant data, packed (elem0, elem1).
    v2f E[5], Yv[5], x3[5];
#pragma unroll
    for (int l = 0; l < 5; ++l) {
        const float Edir0 = X[e0*25 + l*5 + 0], Edir1 = X[e1*25 + l*5 + 0];
        const float Edif0 = X[e0*25 + l*5 + 1], Edif1 = X[e1*25 + l*5 + 1];
        x3[l].x = X[e0*25 + l*5 + 3];  x3[l].y = X[e1*25 + l*5 + 3];
        E[l].x  = (Edir0 + 0.5f * Edif0) * frcp(Edir0 + Edif0);
        E[l].y  = (Edir1 + 0.5f * Edif1) * frcp(Edir1 + Edif1);
        Yv[l].x = Y[e0*5 + l];  Yv[l].y = Y[e1*5 + l];
    }

    v2f ch[3], mm[3], vv[3];
#pragma unroll
    for (int k = 0; k < 3; ++k) {
        ch[k].x = ch0p[e0*3 + k];
        ch[k].y = ch0p[e1*3 + k];
        mm[k] = (v2f)0.0f;
        vv[k] = (v2f)0.0f;
    }

    float p1 = 1.0f, p2 = 1.0f;
    const float B1c = 0.9f,  oB1 = 1.0f - 0.9f;
    const float B2c = 0.999f, oB2 = 1.0f - 0.999f;
    const float LR = 0.02f, EPSc = 1e-8f;

    if (diag) {
        // ---------- fast path: diagonal Sym(Se), Sym(Sa) ----------
        const float SaD0 = Sa[0][0], SaD1 = Sa[1][1], SaD2 = Sa[2][2];
        const float ABn  = Anap + Bnap;
        const float AB0  = A0 + Bb0;

        // Pre-broadcast per-lambda v2f constants.
        v2f AB2[5], Bph2[5], Acd2[5], E2S[5], YES[5];
#pragma unroll
        for (int l = 0; l < 5; ++l) {
            AB2[l]  = bcast(Aph[l] + Bph[l]);
            Bph2[l] = bcast(Bph[l]);
            Acd2[l] = bcast(Acd[l]);
            E2S[l]  = (Se[l][l] * E[l]) * E[l];
            YES[l]  = (Se[l][l] * E[l]) * Yv[l];
        }
        const v2f c1v = bcast(c1), c2v = bcast(c2);
        const v2f Bnapv = bcast(Bnap), ABnv = bcast(ABn);

        for (int t = 0; t < T; ++t) {
            p1 *= B1c; p2 *= B2c;
            const float im   = frcp(1.0f - p1);
            const float sqiv = fsqrt_(frcp(1.0f - p2));
            const float lrim = LR * im;

            const v2f chla = vexp(ch[0]);
            const v2f nap  = vexp(ch[1]);
            const v2f cdom = vexp(ch[2]);

            const v2f bt = Bb0 + Bnap * nap;    // Bb0 + Bnap*nap
            const v2f ct = AB0 + ABn  * nap;    // at + bt

            // even/odd dual accumulators
            v2f Ka = (v2f)0.0f, Kb = (v2f)0.0f;
            v2f KUa = (v2f)0.0f, KUb = (v2f)0.0f;
            v2f s0a = (v2f)0.0f, s0b = (v2f)0.0f;
            v2f s2a = (v2f)0.0f, s2b = (v2f)0.0f;
#pragma unroll
            for (int l = 0; l < 5; ++l) {
                const v2f s   = AB2[l] * chla + (Acd2[l] * cdom + ct);
                const v2f bb  = Bph2[l] * chla + bt;
                const v2f p   = vrcp(s);
                const v2f u   = bb * p;
                const v2f t1  = c1v + c2v * u;       // c1 + c2 u
                const v2f w2  = t1  + c2v * u;       // c1 + 2 c2 u
                const v2f ESr = (t1 * u) * E2S[l] - YES[l];
                const v2f k   = (w2 * p) * ESr;
                const v2f ku  = k * u;
                const v2f inner = Bph2[l] - AB2[l] * u;
                if ((l & 1) == 0) {
                    Ka  += k;
                    KUa += ku;
                    s0a += k * inner;
                    s2a += Acd2[l] * ku;
                } else {
                    Kb  += k;
                    KUb += ku;
                    s0b += k * inner;
                    s2b += Acd2[l] * ku;
                }
            }
            const v2f K  = Ka + Kb;
            const v2f KU = KUa + KUb;
            const v2f s0 = s0a + s0b;
            const v2f s2 = s2a + s2b;
            const v2f s1 = Bnapv * K - ABnv * KU;

            v2f gs[3];
            gs[0] = SaD0 * (ch[0] - xa0) + chla * s0;
            gs[1] = SaD1 * (ch[1] - xa1) + nap  * s1;
            gs[2] = SaD2 * (ch[2] - xa2) - cdom * s2;

#pragma unroll
            for (int k = 0; k < 3; ++k) {
                const v2f g = gs[k];
                mm[k] = B1c * mm[k] + oB1 * g;
                vv[k] = B2c * vv[k] + oB2 * (g * g);
                const v2f den = vsqrt(vv[k]) * sqiv + EPSc;
                ch[k] -= (lrim * mm[k]) * vrcp(den);
            }
        }
    } else {
        // ---------- general path (dense Sym(Se)/Sym(Sa)) ----------
        for (int t = 0; t < T; ++t) {
            p1 *= B1c; p2 *= B2c;
            const float im   = frcp(1.0f - p1);
            const float sqiv = fsqrt_(frcp(1.0f - p2));
            const float lrim = LR * im;

            const v2f chla = vexp(ch[0]);
            const v2f nap  = vexp(ch[1]);
            const v2f cdom = vexp(ch[2]);

            const v2f d0 = ch[0] - xa0, d1 = ch[1] - xa1, d2 = ch[2] - xa2;
            v2f g0 = Sa[0][0]*d0 + Sa[0][1]*d1 + Sa[0][2]*d2;
            v2f g1 = Sa[1][0]*d0 + Sa[1][1]*d1 + Sa[1][2]*d2;
            v2f g2 = Sa[2][0]*d0 + Sa[2][1]*d1 + Sa[2][2]*d2;

            const v2f da1 = Anap * nap;
            const v2f db1 = Bnap * nap;

            v2f av[5], bv[5], wv[5], rv[5];
#pragma unroll
            for (int l = 0; l < 5; ++l) {
                const v2f da0 = Aph[l] * chla;
                const v2f db0 = Bph[l] * chla;
                const v2f da2 = Acd[l] * cdom;
                const v2f a   = A0  + da0 + da2 + da1;
                const v2f bb  = Bb0 + db0 + db1;
                const v2f inv_s = vrcp(a + bb);
                const v2f u     = bb * inv_s;
                const v2f rrs   = (c1 + c2 * u) * u;
                av[l] = a;
                bv[l] = bb;
                rv[l] = rrs * E[l] - Yv[l];
                wv[l] = (c1 + c22 * u) * E[l] * inv_s * inv_s;
            }

            v2f s0 = (v2f)0.0f, s1 = (v2f)0.0f, s2 = (v2f)0.0f;
#pragma unroll
            for (int i = 0; i < 5; ++i) {
                const v2f q = Se[i][0]*rv[0] + Se[i][1]*rv[1] + Se[i][2]*rv[2]
                            + Se[i][3]*rv[3] + Se[i][4]*rv[4];
                const v2f h = wv[i] * q;
                s0 += h * (Bph[i] * av[i] - Aph[i] * bv[i]);
                s1 += h * (Bnap   * av[i] - Anap   * bv[i]);
                s2 += h * (Acd[i] * bv[i]);
            }
            g0 += chla * s0;
            g1 += nap  * s1;
            g2 -= cdom * s2;

            const v2f gs[3] = {g0, g1, g2};
#pragma unroll
            for (int k = 0; k < 3; ++k) {
                const v2f g = gs[k];
                mm[k] = B1c * mm[k] + oB1 * g;
                vv[k] = B2c * vv[k] + oB2 * (g * g);
                const v2f den = vsqrt(vv[k]) * sqiv + EPSc;
                ch[k] -= (lrim * mm[k]) * vrcp(den);
            }
        }
    }

    // Epilogue
    const float kdscale = pfv[9] * 0.9f + pfv[10] * 0.1f;
    const float lam3[3] = {0.025f, 0.5f, 1.15f};

    const v2f chla = vexp(ch[0]);
    const v2f nap  = vexp(ch[1]);
    const v2f cdom = vexp(ch[2]);

#pragma unroll
    for (int ee = 0; ee < 2; ++ee) {
        if (ee == 1 && !valid1) break;
        const int e = ee ? e1 : e0;
        const float chl = ee ? chla.y : chla.x;
        const float np  = ee ? nap.y  : nap.x;
        const float cd  = ee ? cdom.y : cdom.x;

        float o[9];
        o[0] = ee ? ch[0].y : ch[0].x;
#pragma unroll
        for (int l = 0; l < 5; ++l) {
            const float a  = A0  + Aph[l]*chl + Acd[l]*cd + Anap*np;
            const float bb = Bb0 + Bph[l]*chl + Bnap*np;
            const float xx = ee ? x3[l].y : x3[l].x;
            const float sig = frcp(1.0f + fexp(-xx));
            const float mu  = 0.5f + 0.5f * sig;
            o[1 + l] = (a + bb) * frcp(mu) * kdscale;
        }
#pragma unroll
        for (int j = 0; j < 3; ++j) {
            const float bph = pfv[3] * 0.001f * (1.0f + pfv[4] * 0.05f * lam3[j]);
            o[6 + j] = pfv[11] * (bph * chl + Bnap * np);
        }
#pragma unroll
        for (int i = 0; i < 9; ++i) out[e*9 + i] = o[i];
    }
}

extern "C" void kernel_launch(void* const* d_in, const int* in_sizes, int n_in,
                              void* d_out, int out_size, void* d_ws, size_t ws_size,
                              hipStream_t stream) {
    const float* X   = (const float*)d_in[0];
    const float* Y   = (const float*)d_in[1];
    const float* ch0 = (const float*)d_in[2];
    const float* pf  = (const float*)d_in[3];
    const float* xa  = (const float*)d_in[4];
    const float* sa  = (const float*)d_in[5];
    const float* se  = (const float*)d_in[6];
    const int*   ni  = (const int*)d_in[7];
    float* out = (float*)d_out;

    const int B  = in_sizes[0] / 25;
    const int n0 = (B + 1) / 2;
    const int block = 64;
    const int grid = (n0 + block - 1) / block;
    hipLaunchKernelGGL(pe_kernel, dim3(grid), dim3(block), 0, stream,
                       X, Y, ch0, pf, xa, sa, se, ni, out, B, n0);
}

// Round 8
// 95.683 us; speedup vs baseline: 1.6056x; 1.0183x over previous
//
#include <hip/hip_runtime.h>
#include <math.h>

// One thread per TWO batch elements as a packed float2 (v_pk_* fp32).
// R7b: cut the quarter-rate transcendental stream (the dominant issue cost):
//  - Adam: 1/(sqrt(vh)+eps) -> min(rsqrt(v)*sqrt(1-b2^t), 1/eps)
//    (exact in both eps-regimes; 2 trans -> 1 trans per component)
//  - uniform sqiv via single sqrt; exp via 1 packed mul by log2e + raw v_exp_f32
//  - s0 = sum(Bph*k) - sum(AB*ku)  (drops `inner` from the dependent chain)
// General dense path kept as fallback.

typedef float v2f __attribute__((ext_vector_type(2)));

__device__ __forceinline__ float frcp(float x)  { return __builtin_amdgcn_rcpf(x); }
__device__ __forceinline__ float fsqrt_(float x){ return __builtin_amdgcn_sqrtf(x); }
__device__ __forceinline__ float fexp2_(float x){ return __builtin_amdgcn_exp2f(x); }  // v_exp_f32 = 2^x
__device__ __forceinline__ float frsq_(float x) { return __builtin_amdgcn_rsqf(x); }
__device__ __forceinline__ float fexp(float x)  { return __expf(x); }

__device__ __forceinline__ v2f vrcp(v2f x){ v2f r; r.x = frcp(x.x); r.y = frcp(x.y); return r; }
__device__ __forceinline__ v2f vsqrt(v2f x){ v2f r; r.x = fsqrt_(x.x); r.y = fsqrt_(x.y); return r; }
__device__ __forceinline__ v2f vrsq(v2f x){ v2f r; r.x = frsq_(x.x); r.y = frsq_(x.y); return r; }
__device__ __forceinline__ v2f vexp(v2f x){ v2f r; r.x = fexp(x.x); r.y = fexp(x.y); return r; }
// exp(x) = 2^(x*log2e): one packed mul, two raw v_exp_f32
__device__ __forceinline__ v2f vexp_fast(v2f x){
    const v2f xs = x * 1.442695040888963f;
    v2f r; r.x = fexp2_(xs.x); r.y = fexp2_(xs.y); return r;
}
__device__ __forceinline__ v2f vminc(v2f x, float c){
    v2f r; r.x = fminf(x.x, c); r.y = fminf(x.y, c); return r;
}
__device__ __forceinline__ v2f bcast(float x){ v2f r; r.x = x; r.y = x; return r; }

__global__ __launch_bounds__(64)
void pe_kernel(const float* __restrict__ X,      // (B,5,5)
               const float* __restrict__ Y,      // (B,5)
               const float* __restrict__ ch0p,   // (B,1,3)
               const float* __restrict__ pf,     // (14,)
               const float* __restrict__ x_a,    // (3,)
               const float* __restrict__ s_a_inv,// (3,3)
               const float* __restrict__ s_e_inv,// (5,5)
               const int*   __restrict__ n_iter, // (1,)
               float* __restrict__ out,          // (B,9)
               int B, int n0)                    // n0 = ceil(B/2)
{
    const int b = blockIdx.x * blockDim.x + threadIdx.x;
    if (b >= n0) return;

    const bool valid1 = (b + n0) < B;
    const int e0 = b;
    const int e1 = valid1 ? (b + n0) : b;

    const float lam[5] = {-0.275f, 0.025f, 0.5f, 0.7f, 1.15f};

    float pfv[14];
#pragma unroll
    for (int i = 0; i < 14; ++i) pfv[i] = pf[i];

    const float xa0 = x_a[0], xa1 = x_a[1], xa2 = x_a[2];

    float Sa[3][3];
#pragma unroll
    for (int i = 0; i < 3; ++i)
#pragma unroll
        for (int j = 0; j < 3; ++j)
            Sa[i][j] = 0.5f * (s_a_inv[i*3+j] + s_a_inv[j*3+i]);

    float Se[5][5];
#pragma unroll
    for (int i = 0; i < 5; ++i)
#pragma unroll
        for (int j = 0; j < 5; ++j)
            Se[i][j] = 0.5f * (s_e_inv[i*5+j] + s_e_inv[j*5+i]);

    // Wave-uniform structure check.
    bool diag = true;
#pragma unroll
    for (int i = 0; i < 5; ++i)
#pragma unroll
        for (int j = 0; j < 5; ++j)
            if (i != j && Se[i][j] != 0.0f) diag = false;
#pragma unroll
    for (int i = 0; i < 3; ++i)
#pragma unroll
        for (int j = 0; j < 3; ++j)
            if (i != j && Sa[i][j] != 0.0f) diag = false;

    const int T = n_iter[0];

    // Iteration-invariant optics constants (uniform).
    const float A0   = 0.0045f, Bb0 = 0.0012f;
    const float Anap = pfv[12] * 0.005f;
    const float Bnap = pfv[13] * 0.005f;
    const float c1   = pfv[7] * 0.089f;
    const float c2   = pfv[8] * 0.1245f;
    const float c22  = 2.0f * c2;
    float Aph[5], Acd[5], Bph[5];
#pragma unroll
    for (int l = 0; l < 5; ++l) {
        Aph[l] = pfv[0] * 0.05f * (1.0f + pfv[1] * 0.1f * lam[l] + pfv[2] * 0.01f);
        Acd[l] = pfv[5] * 0.1f * fexp(-pfv[6] * 1.7f * lam[l]);
        Bph[l] = pfv[3] * 0.001f * (1.0f + pfv[4] * 0.05f * lam[l]);
    }

    // Per-element iteration-invariant data, packed (elem0, elem1).
    v2f E[5], Yv[5], x3[5];
#pragma unroll
    for (int l = 0; l < 5; ++l) {
        const float Edir0 = X[e0*25 + l*5 + 0], Edir1 = X[e1*25 + l*5 + 0];
        const float Edif0 = X[e0*25 + l*5 + 1], Edif1 = X[e1*25 + l*5 + 1];
        x3[l].x = X[e0*25 + l*5 + 3];  x3[l].y = X[e1*25 + l*5 + 3];
        E[l].x  = (Edir0 + 0.5f * Edif0) * frcp(Edir0 + Edif0);
        E[l].y  = (Edir1 + 0.5f * Edif1) * frcp(Edir1 + Edif1);
        Yv[l].x = Y[e0*5 + l];  Yv[l].y = Y[e1*5 + l];
    }

    v2f ch[3], mm[3], vv[3];
#pragma unroll
    for (int k = 0; k < 3; ++k) {
        ch[k].x = ch0p[e0*3 + k];
        ch[k].y = ch0p[e1*3 + k];
        mm[k] = (v2f)0.0f;
        vv[k] = (v2f)0.0f;
    }

    float p1 = 1.0f, p2 = 1.0f;
    const float B1c = 0.9f,  oB1 = 1.0f - 0.9f;
    const float B2c = 0.999f, oB2 = 1.0f - 0.999f;
    const float LR = 0.02f, EPSc = 1e-8f;
    const float INV_EPS = 1e8f;   // 1/eps: clamp for the rsqrt denominator

    if (diag) {
        // ---------- fast path: diagonal Sym(Se), Sym(Sa) ----------
        const float SaD0 = Sa[0][0], SaD1 = Sa[1][1], SaD2 = Sa[2][2];
        const float ABn  = Anap + Bnap;
        const float AB0  = A0 + Bb0;

        v2f AB2[5], Bph2[5], Acd2[5], E2S[5], YES[5];
#pragma unroll
        for (int l = 0; l < 5; ++l) {
            AB2[l]  = bcast(Aph[l] + Bph[l]);
            Bph2[l] = bcast(Bph[l]);
            Acd2[l] = bcast(Acd[l]);
            E2S[l]  = (Se[l][l] * E[l]) * E[l];
            YES[l]  = (Se[l][l] * E[l]) * Yv[l];
        }
        const v2f c1v = bcast(c1), c2v = bcast(c2);
        const v2f Bnapv = bcast(Bnap), ABnv = bcast(ABn);

        for (int t = 0; t < T; ++t) {
            p1 *= B1c; p2 *= B2c;
            const float lrim = LR * frcp(1.0f - p1);   // LR/(1-b1^t)
            const float sqp2 = fsqrt_(1.0f - p2);      // sqrt(1-b2^t)

            const v2f chla = vexp_fast(ch[0]);
            const v2f nap  = vexp_fast(ch[1]);
            const v2f cdom = vexp_fast(ch[2]);

            const v2f bt = Bb0 + Bnap * nap;
            const v2f ct = AB0 + ABn  * nap;

            v2f Ka = (v2f)0.0f, Kb = (v2f)0.0f;
            v2f KUa = (v2f)0.0f, KUb = (v2f)0.0f;
            v2f s0p = (v2f)0.0f, s0m = (v2f)0.0f;
            v2f s2a = (v2f)0.0f, s2b = (v2f)0.0f;
#pragma unroll
            for (int l = 0; l < 5; ++l) {
                const v2f s   = AB2[l] * chla + (Acd2[l] * cdom + ct);
                const v2f bb  = Bph2[l] * chla + bt;
                const v2f p   = vrcp(s);
                const v2f u   = bb * p;
                const v2f t1  = c1v + c2v * u;       // c1 + c2 u
                const v2f w2  = t1  + c2v * u;       // c1 + 2 c2 u
                const v2f ESr = (t1 * u) * E2S[l] - YES[l];
                const v2f k   = (w2 * p) * ESr;
                const v2f ku  = k * u;
                if ((l & 1) == 0) {
                    Ka  += k;
                    KUa += ku;
                    s2a += Acd2[l] * ku;
                } else {
                    Kb  += k;
                    KUb += ku;
                    s2b += Acd2[l] * ku;
                }
                s0p += Bph2[l] * k;
                s0m += AB2[l]  * ku;
            }
            const v2f K  = Ka + Kb;
            const v2f KU = KUa + KUb;
            const v2f s0 = s0p - s0m;
            const v2f s2 = s2a + s2b;
            const v2f s1 = Bnapv * K - ABnv * KU;

            v2f gs[3];
            gs[0] = SaD0 * (ch[0] - xa0) + chla * s0;
            gs[1] = SaD1 * (ch[1] - xa1) + nap  * s1;
            gs[2] = SaD2 * (ch[2] - xa2) - cdom * s2;

#pragma unroll
            for (int k = 0; k < 3; ++k) {
                const v2f g = gs[k];
                mm[k] = B1c * mm[k] + oB1 * g;
                vv[k] = B2c * vv[k] + oB2 * (g * g);
                // 1/(sqrt(v*iv)+eps) ~= min(rsqrt(v)*sqrt(1-b2^t), 1/eps)
                const v2f dinv = vminc(vrsq(vv[k]) * sqp2, INV_EPS);
                ch[k] -= lrim * (mm[k] * dinv);
            }
        }
    } else {
        // ---------- general path (dense Sym(Se)/Sym(Sa)) ----------
        for (int t = 0; t < T; ++t) {
            p1 *= B1c; p2 *= B2c;
            const float im   = frcp(1.0f - p1);
            const float sqiv = fsqrt_(frcp(1.0f - p2));
            const float lrim = LR * im;

            const v2f chla = vexp(ch[0]);
            const v2f nap  = vexp(ch[1]);
            const v2f cdom = vexp(ch[2]);

            const v2f d0 = ch[0] - xa0, d1 = ch[1] - xa1, d2 = ch[2] - xa2;
            v2f g0 = Sa[0][0]*d0 + Sa[0][1]*d1 + Sa[0][2]*d2;
            v2f g1 = Sa[1][0]*d0 + Sa[1][1]*d1 + Sa[1][2]*d2;
            v2f g2 = Sa[2][0]*d0 + Sa[2][1]*d1 + Sa[2][2]*d2;

            const v2f da1 = Anap * nap;
            const v2f db1 = Bnap * nap;

            v2f av[5], bv[5], wv[5], rv[5];
#pragma unroll
            for (int l = 0; l < 5; ++l) {
                const v2f da0 = Aph[l] * chla;
                const v2f db0 = Bph[l] * chla;
                const v2f da2 = Acd[l] * cdom;
                const v2f a   = A0  + da0 + da2 + da1;
                const v2f bb  = Bb0 + db0 + db1;
                const v2f inv_s = vrcp(a + bb);
                const v2f u     = bb * inv_s;
                const v2f rrs   = (c1 + c2 * u) * u;
                av[l] = a;
                bv[l] = bb;
                rv[l] = rrs * E[l] - Yv[l];
                wv[l] = (c1 + c22 * u) * E[l] * inv_s * inv_s;
            }

            v2f s0 = (v2f)0.0f, s1 = (v2f)0.0f, s2 = (v2f)0.0f;
#pragma unroll
            for (int i = 0; i < 5; ++i) {
                const v2f q = Se[i][0]*rv[0] + Se[i][1]*rv[1] + Se[i][2]*rv[2]
                            + Se[i][3]*rv[3] + Se[i][4]*rv[4];
                const v2f h = wv[i] * q;
                s0 += h * (Bph[i] * av[i] - Aph[i] * bv[i]);
                s1 += h * (Bnap   * av[i] - Anap   * bv[i]);
                s2 += h * (Acd[i] * bv[i]);
            }
            g0 += chla * s0;
            g1 += nap  * s1;
            g2 -= cdom * s2;

            const v2f gs[3] = {g0, g1, g2};
#pragma unroll
            for (int k = 0; k < 3; ++k) {
                const v2f g = gs[k];
                mm[k] = B1c * mm[k] + oB1 * g;
                vv[k] = B2c * vv[k] + oB2 * (g * g);
                const v2f den = vsqrt(vv[k]) * sqiv + EPSc;
                ch[k] -= (lrim * mm[k]) * vrcp(den);
            }
        }
    }

    // Epilogue
    const float kdscale = pfv[9] * 0.9f + pfv[10] * 0.1f;
    const float lam3[3] = {0.025f, 0.5f, 1.15f};

    const v2f chla = vexp(ch[0]);
    const v2f nap  = vexp(ch[1]);
    const v2f cdom = vexp(ch[2]);

#pragma unroll
    for (int ee = 0; ee < 2; ++ee) {
        if (ee == 1 && !valid1) break;
        const int e = ee ? e1 : e0;
        const float chl = ee ? chla.y : chla.x;
        const float np  = ee ? nap.y  : nap.x;
        const float cd  = ee ? cdom.y : cdom.x;

        float o[9];
        o[0] = ee ? ch[0].y : ch[0].x;
#pragma unroll
        for (int l = 0; l < 5; ++l) {
            const float a  = A0  + Aph[l]*chl + Acd[l]*cd + Anap*np;
            const float bb = Bb0 + Bph[l]*chl + Bnap*np;
            const float xx = ee ? x3[l].y : x3[l].x;
            const float sig = frcp(1.0f + fexp(-xx));
            const float mu  = 0.5f + 0.5f * sig;
            o[1 + l] = (a + bb) * frcp(mu) * kdscale;
        }
#pragma unroll
        for (int j = 0; j < 3; ++j) {
            const float bph = pfv[3] * 0.001f * (1.0f + pfv[4] * 0.05f * lam3[j]);
            o[6 + j] = pfv[11] * (bph * chl + Bnap * np);
        }
#pragma unroll
        for (int i = 0; i < 9; ++i) out[e*9 + i] = o[i];
    }
}

extern "C" void kernel_launch(void* const* d_in, const int* in_sizes, int n_in,
                              void* d_out, int out_size, void* d_ws, size_t ws_size,
                              hipStream_t stream) {
    const float* X   = (const float*)d_in[0];
    const float* Y   = (const float*)d_in[1];
    const float* ch0 = (const float*)d_in[2];
    const float* pf  = (const float*)d_in[3];
    const float* xa  = (const float*)d_in[4];
    const float* sa  = (const float*)d_in[5];
    const float* se  = (const float*)d_in[6];
    const int*   ni  = (const int*)d_in[7];
    float* out = (float*)d_out;

    const int B  = in_sizes[0] / 25;
    const int n0 = (B + 1) / 2;
    const int block = 64;
    const int grid = (n0 + block - 1) / block;
    hipLaunchKernelGGL(pe_kernel, dim3(grid), dim3(block), 0, stream,
                       X, Y, ch0, pf, xa, sa, se, ni, out, B, n0);
}

// Round 9
// 94.799 us; speedup vs baseline: 1.6206x; 1.0093x over previous
//
#include <hip/hip_runtime.h>
#include <math.h>

// One thread per TWO batch elements as a packed float2 (v_pk_* fp32).
// R9: batched product-reciprocal for the 5 per-lambda divisions:
//   1/s_i = (prod_{j!=i} s_j) * rcp(prod_j s_j)   (prefix/suffix products)
//   -> 10 quarter-rate trans ops/iter replaced by 2 trans + 15 packed muls.
// Retains R7's: Adam via clamped rsqrt, exp via log2e + v_exp_f32,
// diagonal-Sym(Se)/Sym(Sa) fast path, dense fallback.

typedef float v2f __attribute__((ext_vector_type(2)));

__device__ __forceinline__ float frcp(float x)  { return __builtin_amdgcn_rcpf(x); }
__device__ __forceinline__ float fsqrt_(float x){ return __builtin_amdgcn_sqrtf(x); }
__device__ __forceinline__ float fexp2_(float x){ return __builtin_amdgcn_exp2f(x); }  // v_exp_f32 = 2^x
__device__ __forceinline__ float frsq_(float x) { return __builtin_amdgcn_rsqf(x); }
__device__ __forceinline__ float fexp(float x)  { return __expf(x); }

__device__ __forceinline__ v2f vrcp(v2f x){ v2f r; r.x = frcp(x.x); r.y = frcp(x.y); return r; }
__device__ __forceinline__ v2f vsqrt(v2f x){ v2f r; r.x = fsqrt_(x.x); r.y = fsqrt_(x.y); return r; }
__device__ __forceinline__ v2f vrsq(v2f x){ v2f r; r.x = frsq_(x.x); r.y = frsq_(x.y); return r; }
__device__ __forceinline__ v2f vexp(v2f x){ v2f r; r.x = fexp(x.x); r.y = fexp(x.y); return r; }
__device__ __forceinline__ v2f vexp_fast(v2f x){
    const v2f xs = x * 1.442695040888963f;
    v2f r; r.x = fexp2_(xs.x); r.y = fexp2_(xs.y); return r;
}
__device__ __forceinline__ v2f vminc(v2f x, float c){
    v2f r; r.x = fminf(x.x, c); r.y = fminf(x.y, c); return r;
}
__device__ __forceinline__ v2f bcast(float x){ v2f r; r.x = x; r.y = x; return r; }

__global__ __launch_bounds__(64)
void pe_kernel(const float* __restrict__ X,      // (B,5,5)
               const float* __restrict__ Y,      // (B,5)
               const float* __restrict__ ch0p,   // (B,1,3)
               const float* __restrict__ pf,     // (14,)
               const float* __restrict__ x_a,    // (3,)
               const float* __restrict__ s_a_inv,// (3,3)
               const float* __restrict__ s_e_inv,// (5,5)
               const int*   __restrict__ n_iter, // (1,)
               float* __restrict__ out,          // (B,9)
               int B, int n0)                    // n0 = ceil(B/2)
{
    const int b = blockIdx.x * blockDim.x + threadIdx.x;
    if (b >= n0) return;

    const bool valid1 = (b + n0) < B;
    const int e0 = b;
    const int e1 = valid1 ? (b + n0) : b;

    const float lam[5] = {-0.275f, 0.025f, 0.5f, 0.7f, 1.15f};

    float pfv[14];
#pragma unroll
    for (int i = 0; i < 14; ++i) pfv[i] = pf[i];

    const float xa0 = x_a[0], xa1 = x_a[1], xa2 = x_a[2];

    float Sa[3][3];
#pragma unroll
    for (int i = 0; i < 3; ++i)
#pragma unroll
        for (int j = 0; j < 3; ++j)
            Sa[i][j] = 0.5f * (s_a_inv[i*3+j] + s_a_inv[j*3+i]);

    float Se[5][5];
#pragma unroll
    for (int i = 0; i < 5; ++i)
#pragma unroll
        for (int j = 0; j < 5; ++j)
            Se[i][j] = 0.5f * (s_e_inv[i*5+j] + s_e_inv[j*5+i]);

    // Wave-uniform structure check.
    bool diag = true;
#pragma unroll
    for (int i = 0; i < 5; ++i)
#pragma unroll
        for (int j = 0; j < 5; ++j)
            if (i != j && Se[i][j] != 0.0f) diag = false;
#pragma unroll
    for (int i = 0; i < 3; ++i)
#pragma unroll
        for (int j = 0; j < 3; ++j)
            if (i != j && Sa[i][j] != 0.0f) diag = false;

    const int T = n_iter[0];

    // Iteration-invariant optics constants (uniform).
    const float A0   = 0.0045f, Bb0 = 0.0012f;
    const float Anap = pfv[12] * 0.005f;
    const float Bnap = pfv[13] * 0.005f;
    const float c1   = pfv[7] * 0.089f;
    const float c2   = pfv[8] * 0.1245f;
    const float c22  = 2.0f * c2;
    float Aph[5], Acd[5], Bph[5];
#pragma unroll
    for (int l = 0; l < 5; ++l) {
        Aph[l] = pfv[0] * 0.05f * (1.0f + pfv[1] * 0.1f * lam[l] + pfv[2] * 0.01f);
        Acd[l] = pfv[5] * 0.1f * fexp(-pfv[6] * 1.7f * lam[l]);
        Bph[l] = pfv[3] * 0.001f * (1.0f + pfv[4] * 0.05f * lam[l]);
    }

    // Per-element iteration-invariant data, packed (elem0, elem1).
    v2f E[5], Yv[5], x3[5];
#pragma unroll
    for (int l = 0; l < 5; ++l) {
        const float Edir0 = X[e0*25 + l*5 + 0], Edir1 = X[e1*25 + l*5 + 0];
        const float Edif0 = X[e0*25 + l*5 + 1], Edif1 = X[e1*25 + l*5 + 1];
        x3[l].x = X[e0*25 + l*5 + 3];  x3[l].y = X[e1*25 + l*5 + 3];
        E[l].x  = (Edir0 + 0.5f * Edif0) * frcp(Edir0 + Edif0);
        E[l].y  = (Edir1 + 0.5f * Edif1) * frcp(Edir1 + Edif1);
        Yv[l].x = Y[e0*5 + l];  Yv[l].y = Y[e1*5 + l];
    }

    v2f ch[3], mm[3], vv[3];
#pragma unroll
    for (int k = 0; k < 3; ++k) {
        ch[k].x = ch0p[e0*3 + k];
        ch[k].y = ch0p[e1*3 + k];
        mm[k] = (v2f)0.0f;
        vv[k] = (v2f)0.0f;
    }

    float p1 = 1.0f, p2 = 1.0f;
    const float B1c = 0.9f,  oB1 = 1.0f - 0.9f;
    const float B2c = 0.999f, oB2 = 1.0f - 0.999f;
    const float LR = 0.02f, EPSc = 1e-8f;
    const float INV_EPS = 1e8f;

    if (diag) {
        // ---------- fast path: diagonal Sym(Se), Sym(Sa) ----------
        const float SaD0 = Sa[0][0], SaD1 = Sa[1][1], SaD2 = Sa[2][2];
        const float ABn  = Anap + Bnap;
        const float AB0  = A0 + Bb0;

        v2f AB2[5], Bph2[5], Acd2[5], E2S[5], YES[5];
#pragma unroll
        for (int l = 0; l < 5; ++l) {
            AB2[l]  = bcast(Aph[l] + Bph[l]);
            Bph2[l] = bcast(Bph[l]);
            Acd2[l] = bcast(Acd[l]);
            E2S[l]  = (Se[l][l] * E[l]) * E[l];
            YES[l]  = (Se[l][l] * E[l]) * Yv[l];
        }
        const v2f c1v = bcast(c1), c2v = bcast(c2);
        const v2f Bnapv = bcast(Bnap), ABnv = bcast(ABn);

        for (int t = 0; t < T; ++t) {
            p1 *= B1c; p2 *= B2c;
            const float lrim = LR * frcp(1.0f - p1);   // LR/(1-b1^t)
            const float sqp2 = fsqrt_(1.0f - p2);      // sqrt(1-b2^t)

            const v2f chla = vexp_fast(ch[0]);
            const v2f nap  = vexp_fast(ch[1]);
            const v2f cdom = vexp_fast(ch[2]);

            const v2f bt = Bb0 + Bnap * nap;
            const v2f ct = AB0 + ABn  * nap;

            // Stage s, bb per lambda.
            v2f sv[5], bbv[5];
#pragma unroll
            for (int l = 0; l < 5; ++l) {
                sv[l]  = AB2[l] * chla + (Acd2[l] * cdom + ct);
                bbv[l] = Bph2[l] * chla + bt;
            }

            // Batched reciprocal: 1/s_i = (prod_{j!=i}) * rcp(prod all).
            const v2f P1 = sv[0] * sv[1];
            const v2f P2 = P1 * sv[2];
            const v2f P3 = P2 * sv[3];
            const v2f Pa = P3 * sv[4];
            const v2f S3 = sv[4] * sv[3];
            const v2f S2 = S3 * sv[2];
            const v2f S1 = S2 * sv[1];
            const v2f rP = vrcp(Pa);
            v2f inv[5];
            inv[0] = S1 * rP;
            inv[1] = (sv[0] * S2) * rP;
            inv[2] = (P1 * S3) * rP;
            inv[3] = (P2 * sv[4]) * rP;
            inv[4] = P3 * rP;

            v2f Ka = (v2f)0.0f, Kb = (v2f)0.0f;
            v2f KUa = (v2f)0.0f, KUb = (v2f)0.0f;
            v2f s0p = (v2f)0.0f, s0m = (v2f)0.0f;
            v2f s2a = (v2f)0.0f, s2b = (v2f)0.0f;
#pragma unroll
            for (int l = 0; l < 5; ++l) {
                const v2f u   = bbv[l] * inv[l];
                const v2f t1  = c1v + c2v * u;       // c1 + c2 u
                const v2f w2  = t1  + c2v * u;       // c1 + 2 c2 u
                const v2f ESr = (t1 * u) * E2S[l] - YES[l];
                const v2f k   = (w2 * inv[l]) * ESr;
                const v2f ku  = k * u;
                if ((l & 1) == 0) {
                    Ka  += k;
                    KUa += ku;
                    s2a += Acd2[l] * ku;
                } else {
                    Kb  += k;
                    KUb += ku;
                    s2b += Acd2[l] * ku;
                }
                s0p += Bph2[l] * k;
                s0m += AB2[l]  * ku;
            }
            const v2f K  = Ka + Kb;
            const v2f KU = KUa + KUb;
            const v2f s0 = s0p - s0m;
            const v2f s2 = s2a + s2b;
            const v2f s1 = Bnapv * K - ABnv * KU;

            v2f gs[3];
            gs[0] = SaD0 * (ch[0] - xa0) + chla * s0;
            gs[1] = SaD1 * (ch[1] - xa1) + nap  * s1;
            gs[2] = SaD2 * (ch[2] - xa2) - cdom * s2;

#pragma unroll
            for (int k = 0; k < 3; ++k) {
                const v2f g = gs[k];
                mm[k] = B1c * mm[k] + oB1 * g;
                vv[k] = B2c * vv[k] + oB2 * (g * g);
                const v2f dinv = vminc(vrsq(vv[k]) * sqp2, INV_EPS);
                ch[k] -= lrim * (mm[k] * dinv);
            }
        }
    } else {
        // ---------- general path (dense Sym(Se)/Sym(Sa)) ----------
        for (int t = 0; t < T; ++t) {
            p1 *= B1c; p2 *= B2c;
            const float im   = frcp(1.0f - p1);
            const float sqiv = fsqrt_(frcp(1.0f - p2));
            const float lrim = LR * im;

            const v2f chla = vexp(ch[0]);
            const v2f nap  = vexp(ch[1]);
            const v2f cdom = vexp(ch[2]);

            const v2f d0 = ch[0] - xa0, d1 = ch[1] - xa1, d2 = ch[2] - xa2;
            v2f g0 = Sa[0][0]*d0 + Sa[0][1]*d1 + Sa[0][2]*d2;
            v2f g1 = Sa[1][0]*d0 + Sa[1][1]*d1 + Sa[1][2]*d2;
            v2f g2 = Sa[2][0]*d0 + Sa[2][1]*d1 + Sa[2][2]*d2;

            const v2f da1 = Anap * nap;
            const v2f db1 = Bnap * nap;

            v2f av[5], bv[5], wv[5], rv[5];
#pragma unroll
            for (int l = 0; l < 5; ++l) {
                const v2f da0 = Aph[l] * chla;
                const v2f db0 = Bph[l] * chla;
                const v2f da2 = Acd[l] * cdom;
                const v2f a   = A0  + da0 + da2 + da1;
                const v2f bb  = Bb0 + db0 + db1;
                const v2f inv_s = vrcp(a + bb);
                const v2f u     = bb * inv_s;
                const v2f rrs   = (c1 + c2 * u) * u;
                av[l] = a;
                bv[l] = bb;
                rv[l] = rrs * E[l] - Yv[l];
                wv[l] = (c1 + c22 * u) * E[l] * inv_s * inv_s;
            }

            v2f s0 = (v2f)0.0f, s1 = (v2f)0.0f, s2 = (v2f)0.0f;
#pragma unroll
            for (int i = 0; i < 5; ++i) {
                const v2f q = Se[i][0]*rv[0] + Se[i][1]*rv[1] + Se[i][2]*rv[2]
                            + Se[i][3]*rv[3] + Se[i][4]*rv[4];
                const v2f h = wv[i] * q;
                s0 += h * (Bph[i] * av[i] - Aph[i] * bv[i]);
                s1 += h * (Bnap   * av[i] - Anap   * bv[i]);
                s2 += h * (Acd[i] * bv[i]);
            }
            g0 += chla * s0;
            g1 += nap  * s1;
            g2 -= cdom * s2;

            const v2f gs[3] = {g0, g1, g2};
#pragma unroll
            for (int k = 0; k < 3; ++k) {
                const v2f g = gs[k];
                mm[k] = B1c * mm[k] + oB1 * g;
                vv[k] = B2c * vv[k] + oB2 * (g * g);
                const v2f den = vsqrt(vv[k]) * sqiv + EPSc;
                ch[k] -= (lrim * mm[k]) * vrcp(den);
            }
        }
    }

    // Epilogue
    const float kdscale = pfv[9] * 0.9f + pfv[10] * 0.1f;
    const float lam3[3] = {0.025f, 0.5f, 1.15f};

    const v2f chla = vexp(ch[0]);
    const v2f nap  = vexp(ch[1]);
    const v2f cdom = vexp(ch[2]);

#pragma unroll
    for (int ee = 0; ee < 2; ++ee) {
        if (ee == 1 && !valid1) break;
        const int e = ee ? e1 : e0;
        const float chl = ee ? chla.y : chla.x;
        const float np  = ee ? nap.y  : nap.x;
        const float cd  = ee ? cdom.y : cdom.x;

        float o[9];
        o[0] = ee ? ch[0].y : ch[0].x;
#pragma unroll
        for (int l = 0; l < 5; ++l) {
            const float a  = A0  + Aph[l]*chl + Acd[l]*cd + Anap*np;
            const float bb = Bb0 + Bph[l]*chl + Bnap*np;
            const float xx = ee ? x3[l].y : x3[l].x;
            const float sig = frcp(1.0f + fexp(-xx));
            const float mu  = 0.5f + 0.5f * sig;
            o[1 + l] = (a + bb) * frcp(mu) * kdscale;
        }
#pragma unroll
        for (int j = 0; j < 3; ++j) {
            const float bph = pfv[3] * 0.001f * (1.0f + pfv[4] * 0.05f * lam3[j]);
            o[6 + j] = pfv[11] * (bph * chl + Bnap * np);
        }
#pragma unroll
        for (int i = 0; i < 9; ++i) out[e*9 + i] = o[i];
    }
}

extern "C" void kernel_launch(void* const* d_in, const int* in_sizes, int n_in,
                              void* d_out, int out_size, void* d_ws, size_t ws_size,
                              hipStream_t stream) {
    const float* X   = (const float*)d_in[0];
    const float* Y   = (const float*)d_in[1];
    const float* ch0 = (const float*)d_in[2];
    const float* pf  = (const float*)d_in[3];
    const float* xa  = (const float*)d_in[4];
    const float* sa  = (const float*)d_in[5];
    const float* se  = (const float*)d_in[6];
    const int*   ni  = (const int*)d_in[7];
    float* out = (float*)d_out;

    const int B  = in_sizes[0] / 25;
    const int n0 = (B + 1) / 2;
    const int block = 64;
    const int grid = (n0 + block - 1) / block;
    hipLaunchKernelGGL(pe_kernel, dim3(grid), dim3(block), 0, stream,
                       X, Y, ch0, pf, xa, sa, se, ni, out, B, n0);
}

// Round 10
// 93.595 us; speedup vs baseline: 1.6414x; 1.0129x over previous
//
#include <hip/hip_runtime.h>
#include <math.h>

// One thread per TWO batch elements as a packed float2 (v_pk_* fp32).
// R10: cubic-polynomial collapse of the per-lambda response chain:
//   k = inv * phi(u),  phi(u) = d3 u^3 + d2 u^2 + d1 u + d0  (Horner, 3 fma)
//   d3 = 2 c2^2 E2S, d2 = 3 c1 c2 E2S, d1 = c1^2 E2S - 2 c2 YES, d0 = -c1 YES
//   (iteration-invariant per-lambda coefficients; saves 2 ops + 1 dep level/lambda)
// Retains: batched product-reciprocal, clamped-rsqrt Adam, exp via v_exp_f32,
// diagonal-Sym(Se)/Sym(Sa) fast path, dense fallback.

typedef float v2f __attribute__((ext_vector_type(2)));

__device__ __forceinline__ float frcp(float x)  { return __builtin_amdgcn_rcpf(x); }
__device__ __forceinline__ float fsqrt_(float x){ return __builtin_amdgcn_sqrtf(x); }
__device__ __forceinline__ float fexp2_(float x){ return __builtin_amdgcn_exp2f(x); }  // v_exp_f32 = 2^x
__device__ __forceinline__ float frsq_(float x) { return __builtin_amdgcn_rsqf(x); }
__device__ __forceinline__ float fexp(float x)  { return __expf(x); }

__device__ __forceinline__ v2f vrcp(v2f x){ v2f r; r.x = frcp(x.x); r.y = frcp(x.y); return r; }
__device__ __forceinline__ v2f vsqrt(v2f x){ v2f r; r.x = fsqrt_(x.x); r.y = fsqrt_(x.y); return r; }
__device__ __forceinline__ v2f vrsq(v2f x){ v2f r; r.x = frsq_(x.x); r.y = frsq_(x.y); return r; }
__device__ __forceinline__ v2f vexp(v2f x){ v2f r; r.x = fexp(x.x); r.y = fexp(x.y); return r; }
__device__ __forceinline__ v2f vexp_fast(v2f x){
    const v2f xs = x * 1.442695040888963f;
    v2f r; r.x = fexp2_(xs.x); r.y = fexp2_(xs.y); return r;
}
__device__ __forceinline__ v2f vminc(v2f x, float c){
    v2f r; r.x = fminf(x.x, c); r.y = fminf(x.y, c); return r;
}
__device__ __forceinline__ v2f bcast(float x){ v2f r; r.x = x; r.y = x; return r; }

__global__ __launch_bounds__(64)
void pe_kernel(const float* __restrict__ X,      // (B,5,5)
               const float* __restrict__ Y,      // (B,5)
               const float* __restrict__ ch0p,   // (B,1,3)
               const float* __restrict__ pf,     // (14,)
               const float* __restrict__ x_a,    // (3,)
               const float* __restrict__ s_a_inv,// (3,3)
               const float* __restrict__ s_e_inv,// (5,5)
               const int*   __restrict__ n_iter, // (1,)
               float* __restrict__ out,          // (B,9)
               int B, int n0)                    // n0 = ceil(B/2)
{
    const int b = blockIdx.x * blockDim.x + threadIdx.x;
    if (b >= n0) return;

    const bool valid1 = (b + n0) < B;
    const int e0 = b;
    const int e1 = valid1 ? (b + n0) : b;

    const float lam[5] = {-0.275f, 0.025f, 0.5f, 0.7f, 1.15f};

    float pfv[14];
#pragma unroll
    for (int i = 0; i < 14; ++i) pfv[i] = pf[i];

    const float xa0 = x_a[0], xa1 = x_a[1], xa2 = x_a[2];

    float Sa[3][3];
#pragma unroll
    for (int i = 0; i < 3; ++i)
#pragma unroll
        for (int j = 0; j < 3; ++j)
            Sa[i][j] = 0.5f * (s_a_inv[i*3+j] + s_a_inv[j*3+i]);

    float Se[5][5];
#pragma unroll
    for (int i = 0; i < 5; ++i)
#pragma unroll
        for (int j = 0; j < 5; ++j)
            Se[i][j] = 0.5f * (s_e_inv[i*5+j] + s_e_inv[j*5+i]);

    // Wave-uniform structure check.
    bool diag = true;
#pragma unroll
    for (int i = 0; i < 5; ++i)
#pragma unroll
        for (int j = 0; j < 5; ++j)
            if (i != j && Se[i][j] != 0.0f) diag = false;
#pragma unroll
    for (int i = 0; i < 3; ++i)
#pragma unroll
        for (int j = 0; j < 3; ++j)
            if (i != j && Sa[i][j] != 0.0f) diag = false;

    const int T = n_iter[0];

    // Iteration-invariant optics constants (uniform).
    const float A0   = 0.0045f, Bb0 = 0.0012f;
    const float Anap = pfv[12] * 0.005f;
    const float Bnap = pfv[13] * 0.005f;
    const float c1   = pfv[7] * 0.089f;
    const float c2   = pfv[8] * 0.1245f;
    const float c22  = 2.0f * c2;
    float Aph[5], Acd[5], Bph[5];
#pragma unroll
    for (int l = 0; l < 5; ++l) {
        Aph[l] = pfv[0] * 0.05f * (1.0f + pfv[1] * 0.1f * lam[l] + pfv[2] * 0.01f);
        Acd[l] = pfv[5] * 0.1f * fexp(-pfv[6] * 1.7f * lam[l]);
        Bph[l] = pfv[3] * 0.001f * (1.0f + pfv[4] * 0.05f * lam[l]);
    }

    // Per-element iteration-invariant data, packed (elem0, elem1).
    v2f E[5], Yv[5], x3[5];
#pragma unroll
    for (int l = 0; l < 5; ++l) {
        const float Edir0 = X[e0*25 + l*5 + 0], Edir1 = X[e1*25 + l*5 + 0];
        const float Edif0 = X[e0*25 + l*5 + 1], Edif1 = X[e1*25 + l*5 + 1];
        x3[l].x = X[e0*25 + l*5 + 3];  x3[l].y = X[e1*25 + l*5 + 3];
        E[l].x  = (Edir0 + 0.5f * Edif0) * frcp(Edir0 + Edif0);
        E[l].y  = (Edir1 + 0.5f * Edif1) * frcp(Edir1 + Edif1);
        Yv[l].x = Y[e0*5 + l];  Yv[l].y = Y[e1*5 + l];
    }

    v2f ch[3], mm[3], vv[3];
#pragma unroll
    for (int k = 0; k < 3; ++k) {
        ch[k].x = ch0p[e0*3 + k];
        ch[k].y = ch0p[e1*3 + k];
        mm[k] = (v2f)0.0f;
        vv[k] = (v2f)0.0f;
    }

    float p1 = 1.0f, p2 = 1.0f;
    const float B1c = 0.9f,  oB1 = 1.0f - 0.9f;
    const float B2c = 0.999f, oB2 = 1.0f - 0.999f;
    const float LR = 0.02f, EPSc = 1e-8f;
    const float INV_EPS = 1e8f;

    if (diag) {
        // ---------- fast path: diagonal Sym(Se), Sym(Sa) ----------
        const float SaD0 = Sa[0][0], SaD1 = Sa[1][1], SaD2 = Sa[2][2];
        const float ABn  = Anap + Bnap;
        const float AB0  = A0 + Bb0;

        // Per-lambda broadcast constants + cubic coefficients of
        // phi(u) = (c1+2c2 u)((c1 u + c2 u^2) E2S - YES).
        v2f AB2[5], Bph2[5], Acd2[5], d3[5], d2[5], d1[5], d0[5];
        const float k3 = 2.0f * c2 * c2;
        const float k2 = 3.0f * c1 * c2;
        const float k1 = c1 * c1;
#pragma unroll
        for (int l = 0; l < 5; ++l) {
            AB2[l]  = bcast(Aph[l] + Bph[l]);
            Bph2[l] = bcast(Bph[l]);
            Acd2[l] = bcast(Acd[l]);
            const v2f E2S = (Se[l][l] * E[l]) * E[l];
            const v2f YES = (Se[l][l] * E[l]) * Yv[l];
            d3[l] = k3 * E2S;
            d2[l] = k2 * E2S;
            d1[l] = k1 * E2S - c22 * YES;
            d0[l] = -c1 * YES;
        }
        const v2f Bnapv = bcast(Bnap), ABnv = bcast(ABn);

        for (int t = 0; t < T; ++t) {
            p1 *= B1c; p2 *= B2c;
            const float lrim = LR * frcp(1.0f - p1);   // LR/(1-b1^t)
            const float sqp2 = fsqrt_(1.0f - p2);      // sqrt(1-b2^t)

            const v2f chla = vexp_fast(ch[0]);
            const v2f nap  = vexp_fast(ch[1]);
            const v2f cdom = vexp_fast(ch[2]);

            const v2f bt = Bb0 + Bnap * nap;
            const v2f ct = AB0 + ABn  * nap;

            // Stage s, bb per lambda.
            v2f sv[5], bbv[5];
#pragma unroll
            for (int l = 0; l < 5; ++l) {
                sv[l]  = AB2[l] * chla + (Acd2[l] * cdom + ct);
                bbv[l] = Bph2[l] * chla + bt;
            }

            // Batched reciprocal: 1/s_i = (prod_{j!=i}) * rcp(prod all).
            const v2f P1 = sv[0] * sv[1];
            const v2f P2 = P1 * sv[2];
            const v2f P3 = P2 * sv[3];
            const v2f Pa = P3 * sv[4];
            const v2f S3 = sv[4] * sv[3];
            const v2f S2 = S3 * sv[2];
            const v2f S1 = S2 * sv[1];
            const v2f rP = vrcp(Pa);
            v2f inv[5];
            inv[0] = S1 * rP;
            inv[1] = (sv[0] * S2) * rP;
            inv[2] = (P1 * S3) * rP;
            inv[3] = (P2 * sv[4]) * rP;
            inv[4] = P3 * rP;

            v2f Ka = (v2f)0.0f, Kb = (v2f)0.0f;
            v2f KUa = (v2f)0.0f, KUb = (v2f)0.0f;
            v2f s0p = (v2f)0.0f, s0m = (v2f)0.0f;
            v2f s2a = (v2f)0.0f, s2b = (v2f)0.0f;
#pragma unroll
            for (int l = 0; l < 5; ++l) {
                const v2f u   = bbv[l] * inv[l];
                // phi(u) via Horner: 3 fma
                const v2f phi = ((d3[l] * u + d2[l]) * u + d1[l]) * u + d0[l];
                const v2f k   = inv[l] * phi;
                const v2f ku  = k * u;
                if ((l & 1) == 0) {
                    Ka  += k;
                    KUa += ku;
                    s2a += Acd2[l] * ku;
                } else {
                    Kb  += k;
                    KUb += ku;
                    s2b += Acd2[l] * ku;
                }
                s0p += Bph2[l] * k;
                s0m += AB2[l]  * ku;
            }
            const v2f K  = Ka + Kb;
            const v2f KU = KUa + KUb;
            const v2f s0 = s0p - s0m;
            const v2f s2 = s2a + s2b;
            const v2f s1 = Bnapv * K - ABnv * KU;

            v2f gs[3];
            gs[0] = SaD0 * (ch[0] - xa0) + chla * s0;
            gs[1] = SaD1 * (ch[1] - xa1) + nap  * s1;
            gs[2] = SaD2 * (ch[2] - xa2) - cdom * s2;

#pragma unroll
            for (int k = 0; k < 3; ++k) {
                const v2f g = gs[k];
                mm[k] = B1c * mm[k] + oB1 * g;
                vv[k] = B2c * vv[k] + oB2 * (g * g);
                const v2f dinv = vminc(vrsq(vv[k]) * sqp2, INV_EPS);
                ch[k] -= lrim * (mm[k] * dinv);
            }
        }
    } else {
        // ---------- general path (dense Sym(Se)/Sym(Sa)) ----------
        for (int t = 0; t < T; ++t) {
            p1 *= B1c; p2 *= B2c;
            const float im   = frcp(1.0f - p1);
            const float sqiv = fsqrt_(frcp(1.0f - p2));
            const float lrim = LR * im;

            const v2f chla = vexp(ch[0]);
            const v2f nap  = vexp(ch[1]);
            const v2f cdom = vexp(ch[2]);

            const v2f d0 = ch[0] - xa0, d1 = ch[1] - xa1, d2 = ch[2] - xa2;
            v2f g0 = Sa[0][0]*d0 + Sa[0][1]*d1 + Sa[0][2]*d2;
            v2f g1 = Sa[1][0]*d0 + Sa[1][1]*d1 + Sa[1][2]*d2;
            v2f g2 = Sa[2][0]*d0 + Sa[2][1]*d1 + Sa[2][2]*d2;

            const v2f da1 = Anap * nap;
            const v2f db1 = Bnap * nap;

            v2f av[5], bv[5], wv[5], rv[5];
#pragma unroll
            for (int l = 0; l < 5; ++l) {
                const v2f da0 = Aph[l] * chla;
                const v2f db0 = Bph[l] * chla;
                const v2f da2 = Acd[l] * cdom;
                const v2f a   = A0  + da0 + da2 + da1;
                const v2f bb  = Bb0 + db0 + db1;
                const v2f inv_s = vrcp(a + bb);
                const v2f u     = bb * inv_s;
                const v2f rrs   = (c1 + c2 * u) * u;
                av[l] = a;
                bv[l] = bb;
                rv[l] = rrs * E[l] - Yv[l];
                wv[l] = (c1 + c22 * u) * E[l] * inv_s * inv_s;
            }

            v2f s0 = (v2f)0.0f, s1 = (v2f)0.0f, s2 = (v2f)0.0f;
#pragma unroll
            for (int i = 0; i < 5; ++i) {
                const v2f q = Se[i][0]*rv[0] + Se[i][1]*rv[1] + Se[i][2]*rv[2]
                            + Se[i][3]*rv[3] + Se[i][4]*rv[4];
                const v2f h = wv[i] * q;
                s0 += h * (Bph[i] * av[i] - Aph[i] * bv[i]);
                s1 += h * (Bnap   * av[i] - Anap   * bv[i]);
                s2 += h * (Acd[i] * bv[i]);
            }
            g0 += chla * s0;
            g1 += nap  * s1;
            g2 -= cdom * s2;

            const v2f gs[3] = {g0, g1, g2};
#pragma unroll
            for (int k = 0; k < 3; ++k) {
                const v2f g = gs[k];
                mm[k] = B1c * mm[k] + oB1 * g;
                vv[k] = B2c * vv[k] + oB2 * (g * g);
                const v2f den = vsqrt(vv[k]) * sqiv + EPSc;
                ch[k] -= (lrim * mm[k]) * vrcp(den);
            }
        }
    }

    // Epilogue
    const float kdscale = pfv[9] * 0.9f + pfv[10] * 0.1f;
    const float lam3[3] = {0.025f, 0.5f, 1.15f};

    const v2f chla = vexp(ch[0]);
    const v2f nap  = vexp(ch[1]);
    const v2f cdom = vexp(ch[2]);

#pragma unroll
    for (int ee = 0; ee < 2; ++ee) {
        if (ee == 1 && !valid1) break;
        const int e = ee ? e1 : e0;
        const float chl = ee ? chla.y : chla.x;
        const float np  = ee ? nap.y  : nap.x;
        const float cd  = ee ? cdom.y : cdom.x;

        float o[9];
        o[0] = ee ? ch[0].y : ch[0].x;
#pragma unroll
        for (int l = 0; l < 5; ++l) {
            const float a  = A0  + Aph[l]*chl + Acd[l]*cd + Anap*np;
            const float bb = Bb0 + Bph[l]*chl + Bnap*np;
            const float xx = ee ? x3[l].y : x3[l].x;
            const float sig = frcp(1.0f + fexp(-xx));
            const float mu  = 0.5f + 0.5f * sig;
            o[1 + l] = (a + bb) * frcp(mu) * kdscale;
        }
#pragma unroll
        for (int j = 0; j < 3; ++j) {
            const float bph = pfv[3] * 0.001f * (1.0f + pfv[4] * 0.05f * lam3[j]);
            o[6 + j] = pfv[11] * (bph * chl + Bnap * np);
        }
#pragma unroll
        for (int i = 0; i < 9; ++i) out[e*9 + i] = o[i];
    }
}

extern "C" void kernel_launch(void* const* d_in, const int* in_sizes, int n_in,
                              void* d_out, int out_size, void* d_ws, size_t ws_size,
                              hipStream_t stream) {
    const float* X   = (const float*)d_in[0];
    const float* Y   = (const float*)d_in[1];
    const float* ch0 = (const float*)d_in[2];
    const float* pf  = (const float*)d_in[3];
    const float* xa  = (const float*)d_in[4];
    const float* sa  = (const float*)d_in[5];
    const float* se  = (const float*)d_in[6];
    const int*   ni  = (const int*)d_in[7];
    float* out = (float*)d_out;

    const int B  = in_sizes[0] / 25;
    const int n0 = (B + 1) / 2;
    const int block = 64;
    const int grid = (n0 + block - 1) / block;
    hipLaunchKernelGGL(pe_kernel, dim3(grid), dim3(block), 0, stream,
                       X, Y, ch0, pf, xa, sa, se, ni, out, B, n0);
}